// Round 16
// baseline (11766.797 us; speedup 1.0000x reference)
//
#include <hip/hip_runtime.h>

#define B_ 64
#define T_ 512
#define IN0_ 512
#define H_ 1024
#define C_ 1000
#define NWG 256
#define NTHR 256
#define DRING 8

typedef _Float16 f16;
typedef _Float16 f16x8 __attribute__((ext_vector_type(8)));
typedef _Float16 f16x4 __attribute__((ext_vector_type(4)));
typedef float f32x4 __attribute__((ext_vector_type(4)));

struct Args {
  const float* x;
  const float* Wih[4];
  const float* Whh[4];
  const float* bih[4];
  const float* bhh[4];
  const float* fcw;
  const float* fcb;
  float* out;
  f16* wpack;
  f16* x16;     // [T][B][512] f16
  f16* houts;   // RING: [4 layers][DRING][64][1024] f16 (sc1-written)
  float* h32f;  // [64][1024] f32 final hidden of layer 3 (sc1-written)
  int* flags;   // 256 per-WG monotonic step counters, padded 128B apart
  int* bar;     // [0]=count, [1]=generation (heavy barrier)
};

__device__ __forceinline__ float sigmoid_f(float x) {
  return 1.0f / (1.0f + __expf(-x));
}
__device__ __forceinline__ float tanh_f(float x) {
  return 1.0f - 2.0f / (__expf(2.0f * x) + 1.0f);
}

// HEAVY barrier — R1 VERBATIM (HW-verified). Used twice only.
__device__ __forceinline__ void heavy_barrier(int* bar) {
  __threadfence();
  __syncthreads();
  if (threadIdx.x == 0) {
    int* cnt = bar;
    int* gen = bar + 1;
    int g = __hip_atomic_load(gen, __ATOMIC_RELAXED, __HIP_MEMORY_SCOPE_AGENT);
    int v = __hip_atomic_fetch_add(cnt, 1, __ATOMIC_ACQ_REL, __HIP_MEMORY_SCOPE_AGENT);
    if (v == NWG - 1) {
      __hip_atomic_store(cnt, 0, __ATOMIC_RELAXED, __HIP_MEMORY_SCOPE_AGENT);
      __hip_atomic_store(gen, g + 1, __ATOMIC_RELEASE, __HIP_MEMORY_SCOPE_AGENT);
    } else {
      int cur;
      do {
        __builtin_amdgcn_s_sleep(2);
        cur = __hip_atomic_load(gen, __ATOMIC_ACQUIRE, __HIP_MEMORY_SCOPE_AGENT);
      } while (cur == g);
    }
  }
  __syncthreads();
  __threadfence();
}

// Coherent 16B fragment load — R8..R15 VERBATIM (HW-verified).
union U16B { unsigned long long u[2]; f16x8 v; };
__device__ __forceinline__ f16x8 aload16(const f16* p) {
  unsigned long long* q = (unsigned long long*)p;
  U16B r;
  r.u[0] = __hip_atomic_load(q,     __ATOMIC_RELAXED, __HIP_MEMORY_SCOPE_AGENT);
  r.u[1] = __hip_atomic_load(q + 1, __ATOMIC_RELAXED, __HIP_MEMORY_SCOPE_AGENT);
  return r.v;
}

// Coherent 8B store (sc1, write-through to L3) — R15-verified coalesced path.
__device__ __forceinline__ void astore8(f16* p, unsigned long long v) {
  __hip_atomic_store((unsigned long long*)p, v, __ATOMIC_RELAXED,
                     __HIP_MEMORY_SCOPE_AGENT);
}
union UF32 { float f; unsigned u; };
__device__ __forceinline__ void astore4(float* p, float v) {
  UF32 c; c.f = v;
  __hip_atomic_store((unsigned*)p, c.u, __ATOMIC_RELAXED,
                     __HIP_MEMORY_SCOPE_AGENT);
}

__device__ __forceinline__ int fload(const int* f) {
  return __hip_atomic_load(f, __ATOMIC_RELAXED, __HIP_MEMORY_SCOPE_AGENT);
}

// Packed-weight layer offsets in f16 elements (R6-verified repack layout).
__constant__ __device__ const size_t WOFF_[4] = {0ul, 4718592ul, 11010048ul, 17301504ul};

// LDS reduction slot (R9-verified scalar layout; banks R:0/1 Z:2/3 NX:4/5 NH:6/7).
__device__ __forceinline__ int ridx(int bank, int rb, int i, int lane) {
  return ((bank * 4 + rb) * 4 + i) * 64 + lane;
}

// R15-VERIFIED compute core; sync replaced by point-to-point dataflow:
//  - wait: 64 same-layer flags >= t (h(t-1) broadcast), 64 producer flags
//    >= t+1 (x input ready), 64 consumer flags >= t+1-DRING (ring reuse).
//  - signal: sc1 data stores -> vmcnt(0) drain -> syncthreads -> flag=t+1
//    (R12-verified producer-ordering protocol).
template <int IN, bool XA>
__device__ void run_layer(const Args& a, int layer, int sub, bool is_last,
                          float* red, float* hlds, f16* hstage) {
  constexpr int NKB = (IN + H_) / 32;   // 48 (layer0) or 64
  constexpr int NXB = IN / 32;          // 16 or 32
  constexpr int SLICE = NKB / 4;        // 12 or 16

  const int tid = threadIdx.x;
  const int wave = tid >> 6;            // 0..3
  const int lane = tid & 63;
  const int jc = lane & 15;
  const int kg = lane >> 4;
  const int j = sub * 16 + jc;
  const int wbase = wave * SLICE;
  const int fid = layer * 64 + sub;

  const float bir = a.bih[layer][j], bhr = a.bhh[layer][j];
  const float biz = a.bih[layer][H_ + j], bhz = a.bhh[layer][H_ + j];
  const float bin_ = a.bih[layer][2 * H_ + j], bhn = a.bhh[layer][2 * H_ + j];

  // ---- gather this wave's K-slice weights, all 3 gates (R11-verified) ----
  const f16x8* wpb = (const f16x8*)(a.wpack + WOFF_[layer] +
                                    (size_t)sub * 3 * NKB * 512) + lane;
  f16x8 wfR[SLICE], wfZ[SLICE], wfN[SLICE];
#pragma unroll
  for (int kk = 0; kk < SLICE; ++kk) {
    wfR[kk] = wpb[(size_t)(0 * NKB + wbase + kk) * 64];
    wfZ[kk] = wpb[(size_t)(1 * NKB + wbase + kk) * 64];
    wfN[kk] = wpb[(size_t)(2 * NKB + wbase + kk) * 64];
  }

  f16* hring = a.houts + (size_t)layer * DRING * B_ * H_;
  const f16* xring = XA ? a.houts + (size_t)(layer - 1) * DRING * B_ * H_
                        : (const f16*)nullptr;

  for (int t = 0; t < T_; ++t) {
    // ---- wait on true dependencies only ----
    {
      const int tt = tid;
      if (tt < 64) {
        if (t >= 1) {                           // same-layer peers: h(t-1)
          const int* f = a.flags + (layer * 64 + tt) * 32;
          while (fload(f) < t) __builtin_amdgcn_s_sleep(1);
        }
      } else if (tt < 128) {
        if (XA) {                               // producer layer: x(t)
          const int* f = a.flags + ((layer - 1) * 64 + (tt - 64)) * 32;
          while (fload(f) < t + 1) __builtin_amdgcn_s_sleep(1);
        }
      } else if (tt < 192) {
        if (layer < 3 && t + 1 > DRING) {       // consumer: ring-slot reuse
          const int* f = a.flags + ((layer + 1) * 64 + (tt - 128)) * 32;
          while (fload(f) < t + 1 - DRING) __builtin_amdgcn_s_sleep(1);
        }
      }
      __syncthreads();
    }

    const f16* xbase = XA ? (xring + (size_t)(t % DRING) * B_ * H_)
                          : (a.x16 + (size_t)t * B_ * IN0_);
    const f16* hbase = hring + (size_t)((t + DRING - 1) % DRING) * B_ * H_;
    f16* ho = hring + (size_t)(t % DRING) * B_ * H_;

    f32x4 aR[4], aZ[4], aNX[4], aNH[4];
#pragma unroll
    for (int rb = 0; rb < 4; ++rb) {
      aR[rb] = 0.f; aZ[rb] = 0.f; aNX[rb] = 0.f; aNH[rb] = 0.f;
    }

#define LOADRB(BUF, RB)                                                      \
  do {                                                                       \
    const int arow_ = (RB) * 16 + jc;                                        \
    const f16* xrow_ = xbase + (size_t)arow_ * IN + kg * 8;                  \
    const f16* hrow_ = hbase + (size_t)arow_ * H_ + kg * 8;                  \
    _Pragma("unroll")                                                        \
    for (int kk = 0; kk < SLICE; ++kk) {                                     \
      const int kb_ = wbase + kk;                                            \
      if (kb_ < NXB) {                                                       \
        if constexpr (XA) BUF[kk] = aload16(xrow_ + kb_ * 32);               \
        else              BUF[kk] = *(const f16x8*)(xrow_ + kb_ * 32);       \
      } else {                                                               \
        BUF[kk] = aload16(hrow_ + (kb_ - NXB) * 32);                         \
      }                                                                      \
    }                                                                        \
  } while (0)

#define MFMARB(BUF, RB)                                                      \
  do {                                                                       \
    _Pragma("unroll")                                                        \
    for (int kk = 0; kk < SLICE; ++kk) {                                     \
      const int kb_ = wbase + kk;                                            \
      const bool isx_ = kb_ < NXB;                                           \
      const f16x8 af_ = BUF[kk];                                             \
      aR[RB] = __builtin_amdgcn_mfma_f32_16x16x32_f16(af_, wfR[kk], aR[RB], 0, 0, 0); \
      aZ[RB] = __builtin_amdgcn_mfma_f32_16x16x32_f16(af_, wfZ[kk], aZ[RB], 0, 0, 0); \
      const f16x8 z8_ = {0, 0, 0, 0, 0, 0, 0, 0};                            \
      const f16x8 afx_ = isx_ ? af_ : z8_;                                   \
      const f16x8 afh_ = isx_ ? z8_ : af_;                                   \
      aNX[RB] = __builtin_amdgcn_mfma_f32_16x16x32_f16(afx_, wfN[kk], aNX[RB], 0, 0, 0); \
      aNH[RB] = __builtin_amdgcn_mfma_f32_16x16x32_f16(afh_, wfN[kk], aNH[RB], 0, 0, 0); \
    }                                                                        \
  } while (0)

    {
      f16x8 bufA[SLICE], bufB[SLICE];
      LOADRB(bufA, 0);
      LOADRB(bufB, 1);
      MFMARB(bufA, 0);
      LOADRB(bufA, 2);
      MFMARB(bufB, 1);
      LOADRB(bufB, 3);
      MFMARB(bufA, 2);
      MFMARB(bufB, 3);
    }
#undef LOADRB
#undef MFMARB

    // ---- two-phase scalar-LDS reduction (R11..R15-verified) ----
    if (wave < 2) {
#pragma unroll
      for (int rb = 0; rb < 4; ++rb)
#pragma unroll
        for (int i = 0; i < 4; ++i) {
          red[ridx(0 + wave, rb, i, lane)] = aR[rb][i];
          red[ridx(2 + wave, rb, i, lane)] = aZ[rb][i];
          red[ridx(4 + wave, rb, i, lane)] = aNX[rb][i];
          red[ridx(6 + wave, rb, i, lane)] = aNH[rb][i];
        }
    }
    __syncthreads();
    if (wave >= 2) {
      const int p = wave - 2;
#pragma unroll
      for (int rb = 0; rb < 4; ++rb)
#pragma unroll
        for (int i = 0; i < 4; ++i) {
          red[ridx(0 + p, rb, i, lane)] += aR[rb][i];
          red[ridx(2 + p, rb, i, lane)] += aZ[rb][i];
          red[ridx(4 + p, rb, i, lane)] += aNX[rb][i];
          red[ridx(6 + p, rb, i, lane)] += aNH[rb][i];
        }
    }
    __syncthreads();

    // ---- epilogue: gate math -> LDS stage (h-master in hlds, R14-verified)
    {
#pragma unroll
      for (int i = 0; i < 4; ++i) {
        const int b = wave * 16 + kg * 4 + i;
        const float R  = red[ridx(0, wave, i, lane)] + red[ridx(1, wave, i, lane)];
        const float Z  = red[ridx(2, wave, i, lane)] + red[ridx(3, wave, i, lane)];
        const float NX = red[ridx(4, wave, i, lane)] + red[ridx(5, wave, i, lane)];
        const float NH = red[ridx(6, wave, i, lane)] + red[ridx(7, wave, i, lane)];
        const float r = sigmoid_f(R + bir + bhr);
        const float zz = sigmoid_f(Z + biz + bhz);
        const float nn = tanh_f(NX + bin_ + r * (NH + bhn));
        const float hp = hlds[b * 17 + jc];
        const float hnew = (1.0f - zz) * nn + zz * hp;
        hlds[b * 17 + jc] = hnew;
        hstage[b * 20 + jc] = (f16)hnew;
        if (is_last && t == T_ - 1) astore4(&a.h32f[(size_t)b * H_ + j], hnew);
      }
    }
    __syncthreads();
    // ---- coalesced ho write: one aligned 8B sc1 store per thread (R15) ----
    {
      const int b = tid >> 2;
      const int c = tid & 3;
      const unsigned long long v =
          *(const unsigned long long*)&hstage[b * 20 + c * 4];
      astore8(&ho[(size_t)b * H_ + sub * 16 + c * 4], v);
    }

    // ---- signal: drain data to L3, then publish flag (R12 protocol) ----
    asm volatile("s_waitcnt vmcnt(0) lgkmcnt(0)" ::: "memory");
    __syncthreads();
    if (tid == 0)
      __hip_atomic_store(a.flags + fid * 32, t + 1, __ATOMIC_RELAXED,
                         __HIP_MEMORY_SCOPE_AGENT);
  }
}

__global__ void __launch_bounds__(NTHR, 1) gru_pipeline(Args a) {
  __shared__ float red[8 * 4 * 4 * 64];   // 32 KiB scalar f32 (R9-verified)
  __shared__ float hlds[B_ * 17];         // 4.25 KiB h-master (R14-verified)
  __shared__ f16 hstage[B_ * 20];         // 2.5 KiB h' staging (R15-verified)

  const int tid = threadIdx.x;
  const int gtid = blockIdx.x * NTHR + tid;
  const int NT = NWG * NTHR;

  // ================= Phase 0: prologue (R6..R15 verbatim) =================
  {
    const int nf4 = B_ * T_ * IN0_ / 4;
    for (int i = gtid; i < nf4; i += NT) {
      int k4 = i & 127;
      int q = i >> 7;
      int b = q & 63;
      int t = q >> 6;
      const float4 v = *(const float4*)(a.x + ((size_t)b * T_ + t) * IN0_ + k4 * 4);
      f16x4 o;
      o[0] = (f16)v.x; o[1] = (f16)v.y; o[2] = (f16)v.z; o[3] = (f16)v.w;
      *(f16x4*)(a.x16 + (size_t)i * 4) = o;
    }
  }
  {
    f16x8 z8 = {0, 0, 0, 0, 0, 0, 0, 0};
    for (int i = gtid; i < 4 * DRING * B_ * H_ / 8; i += NT)
      ((f16x8*)a.houts)[i] = z8;
  }
  for (int i = tid; i < B_ * 17; i += NTHR) hlds[i] = 0.f;
  for (int l = 0; l < 4; ++l) {
    const int In = l ? H_ : IN0_;
    const int K = In + H_;
    const int NKB = K / 32;
    const float* Wih = a.Wih[l];
    const float* Whh = a.Whh[l];
    f16* wp = a.wpack + WOFF_[l];
    const int nunits = 3 * H_ * K / 8;
    for (int uu = gtid; uu < nunits; uu += NT) {
      int lane = uu & 63;
      int q = uu >> 6;
      int kb = q % NKB; q /= NKB;
      int gate = q % 3;
      int subb = q / 3;
      int j = subb * 16 + (lane & 15);
      int g = gate * H_ + j;
      int k = kb * 32 + (lane >> 4) * 8;
      const float* src = (k < In) ? (Wih + (size_t)g * In + k)
                                  : (Whh + (size_t)g * H_ + (k - In));
      f16x8 vv;
#pragma unroll
      for (int e = 0; e < 8; ++e) vv[e] = (f16)src[e];
      ((f16x8*)wp)[uu] = vv;
    }
  }

  heavy_barrier(a.bar);   // wbl2+inv once: x16/wpack/ring-zeros now stable

  // ================= Phase 1: dataflow-synced recurrence ==================
  // XCD-local layer mapping: layer = (blockIdx%8)>>1 puts each layer's 64 WGs
  // on 2 XCDs (same-layer flag/h traffic fabric-local). Perf heuristic only.
  const int wg = blockIdx.x;
  const int xslot = wg & 7;
  const int layer = xslot >> 1;
  const int sub = (wg >> 3) * 2 + (xslot & 1);

  if (layer == 0) run_layer<IN0_, false>(a, layer, sub, false, red, hlds, hstage);
  else            run_layer<H_, true>(a, layer, sub, layer == 3, red, hlds, hstage);

  heavy_barrier(a.bar);   // full visibility for h32f before FC

  // ================= Phase 2: final FC (verbatim) ========================
  for (int o = gtid; o < B_ * C_; o += NT) {
    const int b = o / C_;
    const int c = o - b * C_;
    const float* hv = a.h32f + (size_t)b * H_;
    const float* wv = a.fcw + (size_t)c * H_;
    float s = a.fcb[c];
    for (int k = 0; k < H_; k += 4) {
      const float4 h4 = *(const float4*)(hv + k);
      const float4 w4 = *(const float4*)(wv + k);
      s = fmaf(h4.x, w4.x, s);
      s = fmaf(h4.y, w4.y, s);
      s = fmaf(h4.z, w4.z, s);
      s = fmaf(h4.w, w4.w, s);
    }
    a.out[o] = s;
  }
}

extern "C" void kernel_launch(void* const* d_in, const int* in_sizes, int n_in,
                              void* d_out, int out_size, void* d_ws, size_t ws_size,
                              hipStream_t stream) {
  Args a;
  a.x = (const float*)d_in[0];
  for (int l = 0; l < 4; ++l) {
    a.Wih[l] = (const float*)d_in[1 + 4 * l];
    a.Whh[l] = (const float*)d_in[2 + 4 * l];
    a.bih[l] = (const float*)d_in[3 + 4 * l];
    a.bhh[l] = (const float*)d_in[4 + 4 * l];
  }
  a.fcw = (const float*)d_in[17];
  a.fcb = (const float*)d_in[18];
  a.out = (float*)d_out;

  char* ws = (char*)d_ws;
  size_t off = 0;
  a.wpack = (f16*)(ws + off); off += 23592960ul * 2;                   // 45 MiB
  a.x16   = (f16*)(ws + off); off += 16777216ul * 2;                   // 32 MiB
  a.houts = (f16*)(ws + off); off += 4ul * DRING * B_ * H_ * 2;        // 4 MiB
  a.h32f  = (float*)(ws + off); off += (size_t)B_ * H_ * 4;            // 256 KiB
  a.flags = (int*)(ws + off); off += NWG * 32 * sizeof(int);           // 32 KiB
  a.bar   = (int*)(ws + off); off += 256;

  hipMemsetAsync(a.flags, 0, NWG * 32 * sizeof(int) + 256, stream);

  void* params[] = { &a };
  hipError_t err = hipLaunchCooperativeKernel((void*)gru_pipeline, dim3(NWG),
                                              dim3(NTHR), params, 0, stream);
  if (err != hipSuccess) {
    gru_pipeline<<<dim3(NWG), dim3(NTHR), 0, stream>>>(a);
  }
}

// Round 17
// 7983.717 us; speedup vs baseline: 1.4738x; 1.4738x over previous
//
#include <hip/hip_runtime.h>

#define B_ 64
#define T_ 512
#define IN0_ 512
#define H_ 1024
#define C_ 1000
#define NWG 256
#define NTHR 256

typedef _Float16 f16;
typedef _Float16 f16x8 __attribute__((ext_vector_type(8)));
typedef _Float16 f16x4 __attribute__((ext_vector_type(4)));
typedef float f32x4 __attribute__((ext_vector_type(4)));

struct Args {
  const float* x;
  const float* Wih[4];
  const float* Whh[4];
  const float* bih[4];
  const float* bhh[4];
  const float* fcw;
  const float* fcb;
  float* out;
  f16* wpack;
  f16* x16;     // [T][B][512] f16
  f16* hist;    // [4][RM][64][1024] f16 — state s (=h(s-1)) in slot s%RM.
                // RM == T_+1 when ws permits -> write-once, never reused.
  float* h32f;  // [64][1024] f32 final hidden of layer 3 (sc1-written)
  int* flags;   // 256 per-WG monotonic step counters, padded 128B apart
  int* bar;     // [0]=count, [1]=generation (heavy barrier)
  int RM;       // history slots per layer
};

__device__ __forceinline__ float sigmoid_f(float x) {
  return 1.0f / (1.0f + __expf(-x));
}
__device__ __forceinline__ float tanh_f(float x) {
  return 1.0f - 2.0f / (__expf(2.0f * x) + 1.0f);
}

// HEAVY barrier — R1 VERBATIM (HW-verified). Used twice only.
__device__ __forceinline__ void heavy_barrier(int* bar) {
  __threadfence();
  __syncthreads();
  if (threadIdx.x == 0) {
    int* cnt = bar;
    int* gen = bar + 1;
    int g = __hip_atomic_load(gen, __ATOMIC_RELAXED, __HIP_MEMORY_SCOPE_AGENT);
    int v = __hip_atomic_fetch_add(cnt, 1, __ATOMIC_ACQ_REL, __HIP_MEMORY_SCOPE_AGENT);
    if (v == NWG - 1) {
      __hip_atomic_store(cnt, 0, __ATOMIC_RELAXED, __HIP_MEMORY_SCOPE_AGENT);
      __hip_atomic_store(gen, g + 1, __ATOMIC_RELEASE, __HIP_MEMORY_SCOPE_AGENT);
    } else {
      int cur;
      do {
        __builtin_amdgcn_s_sleep(2);
        cur = __hip_atomic_load(gen, __ATOMIC_ACQUIRE, __HIP_MEMORY_SCOPE_AGENT);
      } while (cur == g);
    }
  }
  __syncthreads();
  __threadfence();
}

// Coherent 8B store (sc1, write-through to L3) — R15/R16-verified path.
// Producers write history ONLY via sc1 => no dirty L2 lines ever exist for
// hist addresses; consumers' ordinary demand fills read L3 truth.
__device__ __forceinline__ void astore8(f16* p, unsigned long long v) {
  __hip_atomic_store((unsigned long long*)p, v, __ATOMIC_RELAXED,
                     __HIP_MEMORY_SCOPE_AGENT);
}
union UF32 { float f; unsigned u; };
__device__ __forceinline__ void astore4(float* p, float v) {
  UF32 c; c.f = v;
  __hip_atomic_store((unsigned*)p, c.u, __ATOMIC_RELAXED,
                     __HIP_MEMORY_SCOPE_AGENT);
}

__device__ __forceinline__ int fload(const int* f) {
  return __hip_atomic_load(f, __ATOMIC_RELAXED, __HIP_MEMORY_SCOPE_AGENT);
}

// Packed-weight layer offsets in f16 elements (R6-verified repack layout).
__constant__ __device__ const size_t WOFF_[4] = {0ul, 4718592ul, 11010048ul, 17301504ul};

// LDS reduction slot (R9-verified scalar layout; banks R:0/1 Z:2/3 NX:4/5 NH:6/7).
__device__ __forceinline__ int ridx(int bank, int rb, int i, int lane) {
  return ((bank * 4 + rb) * 4 + i) * 64 + lane;
}

// R16-VERIFIED compute core + dataflow sync. Memory-path change only:
// history is write-once (slot s%RM, RM=T+1 normally), producers store sc1,
// consumers use ORDINARY cached loads (first same-XCD toucher fills L2,
// peers hit L2 — the 64x reader redundancy stops hammering L3).
template <int IN, bool XA>
__device__ void run_layer(const Args& a, int layer, int sub, bool is_last,
                          float* red, float* hlds, f16* hstage) {
  constexpr int NKB = (IN + H_) / 32;   // 48 (layer0) or 64
  constexpr int NXB = IN / 32;          // 16 or 32
  constexpr int SLICE = NKB / 4;        // 12 or 16

  const int tid = threadIdx.x;
  const int wave = tid >> 6;            // 0..3
  const int lane = tid & 63;
  const int jc = lane & 15;
  const int kg = lane >> 4;
  const int j = sub * 16 + jc;
  const int wbase = wave * SLICE;
  const int fid = layer * 64 + sub;
  const int RM = a.RM;

  const float bir = a.bih[layer][j], bhr = a.bhh[layer][j];
  const float biz = a.bih[layer][H_ + j], bhz = a.bhh[layer][H_ + j];
  const float bin_ = a.bih[layer][2 * H_ + j], bhn = a.bhh[layer][2 * H_ + j];

  // ---- gather this wave's K-slice weights, all 3 gates (R11-verified) ----
  const f16x8* wpb = (const f16x8*)(a.wpack + WOFF_[layer] +
                                    (size_t)sub * 3 * NKB * 512) + lane;
  f16x8 wfR[SLICE], wfZ[SLICE], wfN[SLICE];
#pragma unroll
  for (int kk = 0; kk < SLICE; ++kk) {
    wfR[kk] = wpb[(size_t)(0 * NKB + wbase + kk) * 64];
    wfZ[kk] = wpb[(size_t)(1 * NKB + wbase + kk) * 64];
    wfN[kk] = wpb[(size_t)(2 * NKB + wbase + kk) * 64];
  }

  f16* hring = a.hist + (size_t)layer * RM * B_ * H_;
  const f16* xring = XA ? a.hist + (size_t)(layer - 1) * RM * B_ * H_
                        : (const f16*)nullptr;

  for (int t = 0; t < T_; ++t) {
    // ---- wait on true dependencies only (R16-verified protocol) ----
    {
      const int tt = tid;
      if (tt < 64) {
        if (t >= 1) {                           // same-layer peers: h(t-1)
          const int* f = a.flags + (layer * 64 + tt) * 32;
          while (fload(f) < t) __builtin_amdgcn_s_sleep(1);
        }
      } else if (tt < 128) {
        if (XA) {                               // producer layer: x(t) ready
          const int* f = a.flags + ((layer - 1) * 64 + (tt - 64)) * 32;
          while (fload(f) < t + 1) __builtin_amdgcn_s_sleep(1);
        }
      } else if (tt < 192) {
        if (layer < 3 && t + 1 >= RM) {         // slot-reuse guard (RM<T+1 only)
          const int* f = a.flags + ((layer + 1) * 64 + (tt - 128)) * 32;
          while (fload(f) < t + 2 - RM) __builtin_amdgcn_s_sleep(1);
        }
      }
      __syncthreads();
    }

    // state t (=h(t-1)) in slot t%RM; write state t+1 to slot (t+1)%RM.
    const f16* xbase = XA ? (xring + (size_t)((t + 1) % RM) * B_ * H_)
                          : (a.x16 + (size_t)t * B_ * IN0_);
    const f16* hbase = hring + (size_t)(t % RM) * B_ * H_;
    f16* ho = hring + (size_t)((t + 1) % RM) * B_ * H_;

    f32x4 aR[4], aZ[4], aNX[4], aNH[4];
#pragma unroll
    for (int rb = 0; rb < 4; ++rb) {
      aR[rb] = 0.f; aZ[rb] = 0.f; aNX[rb] = 0.f; aNH[rb] = 0.f;
    }

// ORDINARY cached loads (the whole point of write-once history): first
// same-XCD toucher L3-misses and fills L2; the other same-layer WGs hit L2.
#define LOADRB(BUF, RB)                                                      \
  do {                                                                       \
    const int arow_ = (RB) * 16 + jc;                                        \
    const f16* xrow_ = xbase + (size_t)arow_ * IN + kg * 8;                  \
    const f16* hrow_ = hbase + (size_t)arow_ * H_ + kg * 8;                  \
    _Pragma("unroll")                                                        \
    for (int kk = 0; kk < SLICE; ++kk) {                                     \
      const int kb_ = wbase + kk;                                            \
      BUF[kk] = (kb_ < NXB) ? *(const f16x8*)(xrow_ + kb_ * 32)              \
                            : *(const f16x8*)(hrow_ + (kb_ - NXB) * 32);     \
    }                                                                        \
  } while (0)

#define MFMARB(BUF, RB)                                                      \
  do {                                                                       \
    _Pragma("unroll")                                                        \
    for (int kk = 0; kk < SLICE; ++kk) {                                     \
      const int kb_ = wbase + kk;                                            \
      const bool isx_ = kb_ < NXB;                                           \
      const f16x8 af_ = BUF[kk];                                             \
      aR[RB] = __builtin_amdgcn_mfma_f32_16x16x32_f16(af_, wfR[kk], aR[RB], 0, 0, 0); \
      aZ[RB] = __builtin_amdgcn_mfma_f32_16x16x32_f16(af_, wfZ[kk], aZ[RB], 0, 0, 0); \
      const f16x8 z8_ = {0, 0, 0, 0, 0, 0, 0, 0};                            \
      const f16x8 afx_ = isx_ ? af_ : z8_;                                   \
      const f16x8 afh_ = isx_ ? z8_ : af_;                                   \
      aNX[RB] = __builtin_amdgcn_mfma_f32_16x16x32_f16(afx_, wfN[kk], aNX[RB], 0, 0, 0); \
      aNH[RB] = __builtin_amdgcn_mfma_f32_16x16x32_f16(afh_, wfN[kk], aNH[RB], 0, 0, 0); \
    }                                                                        \
  } while (0)

    {
      f16x8 bufA[SLICE], bufB[SLICE];
      LOADRB(bufA, 0);
      LOADRB(bufB, 1);
      MFMARB(bufA, 0);
      LOADRB(bufA, 2);
      MFMARB(bufB, 1);
      LOADRB(bufB, 3);
      MFMARB(bufA, 2);
      MFMARB(bufB, 3);
    }
#undef LOADRB
#undef MFMARB

    // ---- two-phase scalar-LDS reduction (R11..R16-verified) ----
    if (wave < 2) {
#pragma unroll
      for (int rb = 0; rb < 4; ++rb)
#pragma unroll
        for (int i = 0; i < 4; ++i) {
          red[ridx(0 + wave, rb, i, lane)] = aR[rb][i];
          red[ridx(2 + wave, rb, i, lane)] = aZ[rb][i];
          red[ridx(4 + wave, rb, i, lane)] = aNX[rb][i];
          red[ridx(6 + wave, rb, i, lane)] = aNH[rb][i];
        }
    }
    __syncthreads();
    if (wave >= 2) {
      const int p = wave - 2;
#pragma unroll
      for (int rb = 0; rb < 4; ++rb)
#pragma unroll
        for (int i = 0; i < 4; ++i) {
          red[ridx(0 + p, rb, i, lane)] += aR[rb][i];
          red[ridx(2 + p, rb, i, lane)] += aZ[rb][i];
          red[ridx(4 + p, rb, i, lane)] += aNX[rb][i];
          red[ridx(6 + p, rb, i, lane)] += aNH[rb][i];
        }
    }
    __syncthreads();

    // ---- epilogue: gate math -> LDS stage (h-master in hlds, verified) ----
    {
#pragma unroll
      for (int i = 0; i < 4; ++i) {
        const int b = wave * 16 + kg * 4 + i;
        const float R  = red[ridx(0, wave, i, lane)] + red[ridx(1, wave, i, lane)];
        const float Z  = red[ridx(2, wave, i, lane)] + red[ridx(3, wave, i, lane)];
        const float NX = red[ridx(4, wave, i, lane)] + red[ridx(5, wave, i, lane)];
        const float NH = red[ridx(6, wave, i, lane)] + red[ridx(7, wave, i, lane)];
        const float r = sigmoid_f(R + bir + bhr);
        const float zz = sigmoid_f(Z + biz + bhz);
        const float nn = tanh_f(NX + bin_ + r * (NH + bhn));
        const float hp = hlds[b * 17 + jc];
        const float hnew = (1.0f - zz) * nn + zz * hp;
        hlds[b * 17 + jc] = hnew;
        hstage[b * 20 + jc] = (f16)hnew;
        if (is_last && t == T_ - 1) astore4(&a.h32f[(size_t)b * H_ + j], hnew);
      }
    }
    __syncthreads();
    // ---- coalesced h write: one aligned 8B sc1 store per thread ----
    {
      const int b = tid >> 2;
      const int c = tid & 3;
      const unsigned long long v =
          *(const unsigned long long*)&hstage[b * 20 + c * 4];
      astore8(&ho[(size_t)b * H_ + sub * 16 + c * 4], v);
    }

    // ---- signal: drain sc1 data to L3, then publish flag (R12 protocol) ----
    asm volatile("s_waitcnt vmcnt(0) lgkmcnt(0)" ::: "memory");
    __syncthreads();
    if (tid == 0)
      __hip_atomic_store(a.flags + fid * 32, t + 1, __ATOMIC_RELAXED,
                         __HIP_MEMORY_SCOPE_AGENT);
  }
}

__global__ void __launch_bounds__(NTHR, 1) gru_pipeline(Args a) {
  __shared__ float red[8 * 4 * 4 * 64];   // 32 KiB scalar f32 (R9-verified)
  __shared__ float hlds[B_ * 17];         // 4.25 KiB h-master (R14-verified)
  __shared__ f16 hstage[B_ * 20];         // 2.5 KiB h' staging (R15-verified)

  const int tid = threadIdx.x;
  const int gtid = blockIdx.x * NTHR + tid;
  const int NT = NWG * NTHR;

  // ================= Phase 0: prologue (R6..R16 verbatim) =================
  {
    const int nf4 = B_ * T_ * IN0_ / 4;
    for (int i = gtid; i < nf4; i += NT) {
      int k4 = i & 127;
      int q = i >> 7;
      int b = q & 63;
      int t = q >> 6;
      const float4 v = *(const float4*)(a.x + ((size_t)b * T_ + t) * IN0_ + k4 * 4);
      f16x4 o;
      o[0] = (f16)v.x; o[1] = (f16)v.y; o[2] = (f16)v.z; o[3] = (f16)v.w;
      *(f16x4*)(a.x16 + (size_t)i * 4) = o;
    }
  }
  // zero ONLY state-0 slots (h(-1)=0) of each layer's history.
  {
    f16x8 z8 = {0, 0, 0, 0, 0, 0, 0, 0};
    for (int i = gtid; i < 4 * B_ * H_ / 8; i += NT) {
      int l = i / (B_ * H_ / 8);
      int o = i - l * (B_ * H_ / 8);
      ((f16x8*)(a.hist + (size_t)l * a.RM * B_ * H_))[o] = z8;
    }
  }
  for (int i = tid; i < B_ * 17; i += NTHR) hlds[i] = 0.f;
  for (int l = 0; l < 4; ++l) {
    const int In = l ? H_ : IN0_;
    const int K = In + H_;
    const int NKB = K / 32;
    const float* Wih = a.Wih[l];
    const float* Whh = a.Whh[l];
    f16* wp = a.wpack + WOFF_[l];
    const int nunits = 3 * H_ * K / 8;
    for (int uu = gtid; uu < nunits; uu += NT) {
      int lane = uu & 63;
      int q = uu >> 6;
      int kb = q % NKB; q /= NKB;
      int gate = q % 3;
      int subb = q / 3;
      int j = subb * 16 + (lane & 15);
      int g = gate * H_ + j;
      int k = kb * 32 + (lane >> 4) * 8;
      const float* src = (k < In) ? (Wih + (size_t)g * In + k)
                                  : (Whh + (size_t)g * H_ + (k - In));
      f16x8 vv;
#pragma unroll
      for (int e = 0; e < 8; ++e) vv[e] = (f16)src[e];
      ((f16x8*)wp)[uu] = vv;
    }
  }

  heavy_barrier(a.bar);   // wbl2+inv once: x16/wpack/state-0 now in L3, caches clean

  // ================= Phase 1: dataflow-synced recurrence ==================
  const int wg = blockIdx.x;
  const int xslot = wg & 7;
  const int layer = xslot >> 1;
  const int sub = (wg >> 3) * 2 + (xslot & 1);

  if (layer == 0) run_layer<IN0_, false>(a, layer, sub, false, red, hlds, hstage);
  else            run_layer<H_, true>(a, layer, sub, layer == 3, red, hlds, hstage);

  heavy_barrier(a.bar);   // full visibility for h32f before FC

  // ================= Phase 2: final FC (verbatim) ========================
  for (int o = gtid; o < B_ * C_; o += NT) {
    const int b = o / C_;
    const int c = o - b * C_;
    const float* hv = a.h32f + (size_t)b * H_;
    const float* wv = a.fcw + (size_t)c * H_;
    float s = a.fcb[c];
    for (int k = 0; k < H_; k += 4) {
      const float4 h4 = *(const float4*)(hv + k);
      const float4 w4 = *(const float4*)(wv + k);
      s = fmaf(h4.x, w4.x, s);
      s = fmaf(h4.y, w4.y, s);
      s = fmaf(h4.z, w4.z, s);
      s = fmaf(h4.w, w4.w, s);
    }
    a.out[o] = s;
  }
}

extern "C" void kernel_launch(void* const* d_in, const int* in_sizes, int n_in,
                              void* d_out, int out_size, void* d_ws, size_t ws_size,
                              hipStream_t stream) {
  Args a;
  a.x = (const float*)d_in[0];
  for (int l = 0; l < 4; ++l) {
    a.Wih[l] = (const float*)d_in[1 + 4 * l];
    a.Whh[l] = (const float*)d_in[2 + 4 * l];
    a.bih[l] = (const float*)d_in[3 + 4 * l];
    a.bhh[l] = (const float*)d_in[4 + 4 * l];
  }
  a.fcw = (const float*)d_in[17];
  a.fcb = (const float*)d_in[18];
  a.out = (float*)d_out;

  // Fixed allocations:
  const size_t fixed = 23592960ul * 2        // wpack 45 MiB
                     + 16777216ul * 2        // x16 32 MiB
                     + (size_t)B_ * H_ * 4   // h32f
                     + NWG * 32 * sizeof(int) + 256;
  // Largest history depth that fits (RM = T_+1 -> write-once, no reuse).
  const int cand[] = {T_ + 1, 257, 129, 65, 33, 17};
  int RM = 17;
  for (int i = 0; i < 6; ++i) {
    size_t need = fixed + 4ul * cand[i] * B_ * H_ * 2;
    if (need <= ws_size) { RM = cand[i]; break; }
  }
  a.RM = RM;

  char* ws = (char*)d_ws;
  size_t off = 0;
  a.wpack = (f16*)(ws + off); off += 23592960ul * 2;
  a.x16   = (f16*)(ws + off); off += 16777216ul * 2;
  a.hist  = (f16*)(ws + off); off += 4ul * RM * B_ * H_ * 2;
  a.h32f  = (float*)(ws + off); off += (size_t)B_ * H_ * 4;
  a.flags = (int*)(ws + off); off += NWG * 32 * sizeof(int);
  a.bar   = (int*)(ws + off); off += 256;

  hipMemsetAsync(a.flags, 0, NWG * 32 * sizeof(int) + 256, stream);

  void* params[] = { &a };
  hipError_t err = hipLaunchCooperativeKernel((void*)gru_pipeline, dim3(NWG),
                                              dim3(NTHR), params, 0, stream);
  if (err != hipSuccess) {
    gru_pipeline<<<dim3(NWG), dim3(NTHR), 0, stream>>>(a);
  }
}

// Round 18
// 7777.020 us; speedup vs baseline: 1.5130x; 1.0266x over previous
//
#include <hip/hip_runtime.h>

#define B_ 64
#define T_ 512
#define IN0_ 512
#define H_ 1024
#define C_ 1000
#define NWG 256
#define NTHR 256

typedef _Float16 f16;
typedef _Float16 f16x8 __attribute__((ext_vector_type(8)));
typedef _Float16 f16x4 __attribute__((ext_vector_type(4)));
typedef float f32x4 __attribute__((ext_vector_type(4)));

struct Args {
  const float* x;
  const float* Wih[4];
  const float* Whh[4];
  const float* bih[4];
  const float* bhh[4];
  const float* fcw;
  const float* fcb;
  float* out;
  f16* wpack;
  f16* x16;     // [T][B][512] f16
  f16* hist;    // [4][RM][64][1024] f16 — state s (=h(s-1)) in slot s%RM
  float* h32f;  // [64][1024] f32 final hidden of layer 3 (sc1-written)
  int* flags;   // 256 per-WG monotonic step counters, padded 128B apart
  int* clk;     // 4 layer clocks (sub-0 aggregated), padded 128B apart
  int* bar;     // [0]=count, [1]=generation (heavy barrier)
  int RM;       // history slots per layer
};

__device__ __forceinline__ float sigmoid_f(float x) {
  return 1.0f / (1.0f + __expf(-x));
}
__device__ __forceinline__ float tanh_f(float x) {
  return 1.0f - 2.0f / (__expf(2.0f * x) + 1.0f);
}

// HEAVY barrier — R1 VERBATIM (HW-verified). Used twice only.
__device__ __forceinline__ void heavy_barrier(int* bar) {
  __threadfence();
  __syncthreads();
  if (threadIdx.x == 0) {
    int* cnt = bar;
    int* gen = bar + 1;
    int g = __hip_atomic_load(gen, __ATOMIC_RELAXED, __HIP_MEMORY_SCOPE_AGENT);
    int v = __hip_atomic_fetch_add(cnt, 1, __ATOMIC_ACQ_REL, __HIP_MEMORY_SCOPE_AGENT);
    if (v == NWG - 1) {
      __hip_atomic_store(cnt, 0, __ATOMIC_RELAXED, __HIP_MEMORY_SCOPE_AGENT);
      __hip_atomic_store(gen, g + 1, __ATOMIC_RELEASE, __HIP_MEMORY_SCOPE_AGENT);
    } else {
      int cur;
      do {
        __builtin_amdgcn_s_sleep(2);
        cur = __hip_atomic_load(gen, __ATOMIC_ACQUIRE, __HIP_MEMORY_SCOPE_AGENT);
      } while (cur == g);
    }
  }
  __syncthreads();
  __threadfence();
}

// Coherent 8B store (sc1, write-through to L3) — R15..R17-verified path.
__device__ __forceinline__ void astore8(f16* p, unsigned long long v) {
  __hip_atomic_store((unsigned long long*)p, v, __ATOMIC_RELAXED,
                     __HIP_MEMORY_SCOPE_AGENT);
}
union UF32 { float f; unsigned u; };
__device__ __forceinline__ void astore4(float* p, float v) {
  UF32 c; c.f = v;
  __hip_atomic_store((unsigned*)p, c.u, __ATOMIC_RELAXED,
                     __HIP_MEMORY_SCOPE_AGENT);
}

__device__ __forceinline__ int fload(const int* f) {
  return __hip_atomic_load(f, __ATOMIC_RELAXED, __HIP_MEMORY_SCOPE_AGENT);
}
__device__ __forceinline__ void fstore(int* f, int v) {
  __hip_atomic_store(f, v, __ATOMIC_RELAXED, __HIP_MEMORY_SCOPE_AGENT);
}

// Packed-weight layer offsets in f16 elements (R6-verified repack layout).
__constant__ __device__ const size_t WOFF_[4] = {0ul, 4718592ul, 11010048ul, 17301504ul};

// LDS reduction slot (R9-verified scalar layout; banks R:0/1 Z:2/3 NX:4/5 NH:6/7).
__device__ __forceinline__ int ridx(int bank, int rb, int i, int lane) {
  return ((bank * 4 + rb) * 4 + i) * 64 + lane;
}

// R17-VERIFIED compute core + write-once history. Sync changes only:
//  - per-LAYER clock aggregated by sub==0 (64-lane raw-flag poll, 1 wave),
//    everyone else polls ONE clock word with ONE lane (poll traffic /30).
//  - per-WAVE waits: x-waves gate on producer clock, h-waves on own-layer
//    clock; x work overlaps peer waiting (no joint pre-step barrier —
//    the reduction barrier chain keeps LDS buffers race-free).
template <int IN, bool XA>
__device__ void run_layer(const Args& a, int layer, int sub, bool is_last,
                          float* red, float* hlds, f16* hstage) {
  constexpr int NKB = (IN + H_) / 32;   // 48 (layer0) or 64
  constexpr int NXB = IN / 32;          // 16 or 32
  constexpr int SLICE = NKB / 4;        // 12 or 16
  constexpr int HSTART = (IN == IN0_) ? 1 : 2;  // first wave touching h

  const int tid = threadIdx.x;
  const int wave = tid >> 6;            // 0..3
  const int lane = tid & 63;
  const int jc = lane & 15;
  const int kg = lane >> 4;
  const int j = sub * 16 + jc;
  const int wbase = wave * SLICE;
  const int fid = layer * 64 + sub;
  const int RM = a.RM;

  const float bir = a.bih[layer][j], bhr = a.bhh[layer][j];
  const float biz = a.bih[layer][H_ + j], bhz = a.bhh[layer][H_ + j];
  const float bin_ = a.bih[layer][2 * H_ + j], bhn = a.bhh[layer][2 * H_ + j];

  // ---- gather this wave's K-slice weights, all 3 gates (R11-verified) ----
  const f16x8* wpb = (const f16x8*)(a.wpack + WOFF_[layer] +
                                    (size_t)sub * 3 * NKB * 512) + lane;
  f16x8 wfR[SLICE], wfZ[SLICE], wfN[SLICE];
#pragma unroll
  for (int kk = 0; kk < SLICE; ++kk) {
    wfR[kk] = wpb[(size_t)(0 * NKB + wbase + kk) * 64];
    wfZ[kk] = wpb[(size_t)(1 * NKB + wbase + kk) * 64];
    wfN[kk] = wpb[(size_t)(2 * NKB + wbase + kk) * 64];
  }

  f16* hring = a.hist + (size_t)layer * RM * B_ * H_;
  const f16* xring = XA ? a.hist + (size_t)(layer - 1) * RM * B_ * H_
                        : (const f16*)nullptr;

  for (int t = 0; t < T_; ++t) {
    // ---- per-wave dataflow waits (clock-aggregated) ----
    if (sub == 0) {
      if (wave >= HSTART) {
        if (t >= 1) {                    // raw peer flags, lane l <-> peer l
          const int* f = a.flags + (layer * 64 + lane) * 32;
          while (fload(f) < t) __builtin_amdgcn_s_sleep(1);
        }
        if (wave == HSTART && lane == 0)
          fstore(a.clk + layer * 32, t); // publish layer clock
      } else if (XA) {
        if (lane == 0) {                 // producer clock for x(t)
          const int* c = a.clk + (layer - 1) * 32;
          while (fload(c) < t + 1) __builtin_amdgcn_s_sleep(1);
        }
      }
    } else {
      if (wave >= HSTART) {
        if (t >= 1 && lane == 0) {       // own-layer clock
          const int* c = a.clk + layer * 32;
          while (fload(c) < t) __builtin_amdgcn_s_sleep(1);
        }
      } else if (XA) {
        if (lane == 0) {                 // producer clock
          const int* c = a.clk + (layer - 1) * 32;
          while (fload(c) < t + 1) __builtin_amdgcn_s_sleep(1);
        }
      }
    }
    // ring-reuse guard (dead code when RM == T_+1):
    if (wave == 3 && lane == 1 && layer < 3 && t + 1 >= RM) {
      const int* c = a.clk + (layer + 1) * 32;
      while (fload(c) < t + 2 - RM) __builtin_amdgcn_s_sleep(1);
    }

    // state t (=h(t-1)) in slot t%RM; write state t+1 to slot (t+1)%RM.
    const f16* xbase = XA ? (xring + (size_t)((t + 1) % RM) * B_ * H_)
                          : (a.x16 + (size_t)t * B_ * IN0_);
    const f16* hbase = hring + (size_t)(t % RM) * B_ * H_;
    f16* ho = hring + (size_t)((t + 1) % RM) * B_ * H_;

    f32x4 aR[4], aZ[4], aNX[4], aNH[4];
#pragma unroll
    for (int rb = 0; rb < 4; ++rb) {
      aR[rb] = 0.f; aZ[rb] = 0.f; aNX[rb] = 0.f; aNH[rb] = 0.f;
    }

// ORDINARY cached loads (write-once history — R17-verified).
#define LOADRB(BUF, RB)                                                      \
  do {                                                                       \
    const int arow_ = (RB) * 16 + jc;                                        \
    const f16* xrow_ = xbase + (size_t)arow_ * IN + kg * 8;                  \
    const f16* hrow_ = hbase + (size_t)arow_ * H_ + kg * 8;                  \
    _Pragma("unroll")                                                        \
    for (int kk = 0; kk < SLICE; ++kk) {                                     \
      const int kb_ = wbase + kk;                                            \
      BUF[kk] = (kb_ < NXB) ? *(const f16x8*)(xrow_ + kb_ * 32)              \
                            : *(const f16x8*)(hrow_ + (kb_ - NXB) * 32);     \
    }                                                                        \
  } while (0)

#define MFMARB(BUF, RB)                                                      \
  do {                                                                       \
    _Pragma("unroll")                                                        \
    for (int kk = 0; kk < SLICE; ++kk) {                                     \
      const int kb_ = wbase + kk;                                            \
      const bool isx_ = kb_ < NXB;                                           \
      const f16x8 af_ = BUF[kk];                                             \
      aR[RB] = __builtin_amdgcn_mfma_f32_16x16x32_f16(af_, wfR[kk], aR[RB], 0, 0, 0); \
      aZ[RB] = __builtin_amdgcn_mfma_f32_16x16x32_f16(af_, wfZ[kk], aZ[RB], 0, 0, 0); \
      const f16x8 z8_ = {0, 0, 0, 0, 0, 0, 0, 0};                            \
      const f16x8 afx_ = isx_ ? af_ : z8_;                                   \
      const f16x8 afh_ = isx_ ? z8_ : af_;                                   \
      aNX[RB] = __builtin_amdgcn_mfma_f32_16x16x32_f16(afx_, wfN[kk], aNX[RB], 0, 0, 0); \
      aNH[RB] = __builtin_amdgcn_mfma_f32_16x16x32_f16(afh_, wfN[kk], aNH[RB], 0, 0, 0); \
    }                                                                        \
  } while (0)

    {
      f16x8 bufA[SLICE], bufB[SLICE];
      LOADRB(bufA, 0);
      LOADRB(bufB, 1);
      MFMARB(bufA, 0);
      LOADRB(bufA, 2);
      MFMARB(bufB, 1);
      LOADRB(bufB, 3);
      MFMARB(bufA, 2);
      MFMARB(bufB, 3);
    }
#undef LOADRB
#undef MFMARB

    // ---- two-phase scalar-LDS reduction (R11..R17-verified) ----
    if (wave < 2) {
#pragma unroll
      for (int rb = 0; rb < 4; ++rb)
#pragma unroll
        for (int i = 0; i < 4; ++i) {
          red[ridx(0 + wave, rb, i, lane)] = aR[rb][i];
          red[ridx(2 + wave, rb, i, lane)] = aZ[rb][i];
          red[ridx(4 + wave, rb, i, lane)] = aNX[rb][i];
          red[ridx(6 + wave, rb, i, lane)] = aNH[rb][i];
        }
    }
    __syncthreads();
    if (wave >= 2) {
      const int p = wave - 2;
#pragma unroll
      for (int rb = 0; rb < 4; ++rb)
#pragma unroll
        for (int i = 0; i < 4; ++i) {
          red[ridx(0 + p, rb, i, lane)] += aR[rb][i];
          red[ridx(2 + p, rb, i, lane)] += aZ[rb][i];
          red[ridx(4 + p, rb, i, lane)] += aNX[rb][i];
          red[ridx(6 + p, rb, i, lane)] += aNH[rb][i];
        }
    }
    __syncthreads();

    // ---- epilogue: gate math -> LDS stage (R14/R15-verified) ----
    {
#pragma unroll
      for (int i = 0; i < 4; ++i) {
        const int b = wave * 16 + kg * 4 + i;
        const float R  = red[ridx(0, wave, i, lane)] + red[ridx(1, wave, i, lane)];
        const float Z  = red[ridx(2, wave, i, lane)] + red[ridx(3, wave, i, lane)];
        const float NX = red[ridx(4, wave, i, lane)] + red[ridx(5, wave, i, lane)];
        const float NH = red[ridx(6, wave, i, lane)] + red[ridx(7, wave, i, lane)];
        const float r = sigmoid_f(R + bir + bhr);
        const float zz = sigmoid_f(Z + biz + bhz);
        const float nn = tanh_f(NX + bin_ + r * (NH + bhn));
        const float hp = hlds[b * 17 + jc];
        const float hnew = (1.0f - zz) * nn + zz * hp;
        hlds[b * 17 + jc] = hnew;
        hstage[b * 20 + jc] = (f16)hnew;
        if (is_last && t == T_ - 1) astore4(&a.h32f[(size_t)b * H_ + j], hnew);
      }
    }
    __syncthreads();
    // ---- coalesced h write: one aligned 8B sc1 store per thread ----
    {
      const int b = tid >> 2;
      const int c = tid & 3;
      const unsigned long long v =
          *(const unsigned long long*)&hstage[b * 20 + c * 4];
      astore8(&ho[(size_t)b * H_ + sub * 16 + c * 4], v);
    }

    // ---- signal: drain sc1 data to L3, then publish flag (R12 protocol) ----
    asm volatile("s_waitcnt vmcnt(0) lgkmcnt(0)" ::: "memory");
    __syncthreads();
    if (tid == 0) fstore(a.flags + fid * 32, t + 1);
  }

  // final clock publish (consumers' last x-wait needs clk >= T_)
  if (sub == 0 && layer < 3 && wave == 0) {
    const int* f = a.flags + (layer * 64 + lane) * 32;
    while (fload(f) < T_) __builtin_amdgcn_s_sleep(1);
    if (lane == 0) fstore(a.clk + layer * 32, T_);
  }
}

__global__ void __launch_bounds__(NTHR, 1) gru_pipeline(Args a) {
  __shared__ float red[8 * 4 * 4 * 64];   // 32 KiB scalar f32 (R9-verified)
  __shared__ float hlds[B_ * 17];         // 4.25 KiB h-master (R14-verified)
  __shared__ f16 hstage[B_ * 20];         // 2.5 KiB h' staging (R15-verified)

  const int tid = threadIdx.x;
  const int gtid = blockIdx.x * NTHR + tid;
  const int NT = NWG * NTHR;

  // ================= Phase 0: prologue (R6..R17 verbatim) =================
  {
    const int nf4 = B_ * T_ * IN0_ / 4;
    for (int i = gtid; i < nf4; i += NT) {
      int k4 = i & 127;
      int q = i >> 7;
      int b = q & 63;
      int t = q >> 6;
      const float4 v = *(const float4*)(a.x + ((size_t)b * T_ + t) * IN0_ + k4 * 4);
      f16x4 o;
      o[0] = (f16)v.x; o[1] = (f16)v.y; o[2] = (f16)v.z; o[3] = (f16)v.w;
      *(f16x4*)(a.x16 + (size_t)i * 4) = o;
    }
  }
  // zero ONLY state-0 slots (h(-1)=0) of each layer's history.
  {
    f16x8 z8 = {0, 0, 0, 0, 0, 0, 0, 0};
    for (int i = gtid; i < 4 * B_ * H_ / 8; i += NT) {
      int l = i / (B_ * H_ / 8);
      int o = i - l * (B_ * H_ / 8);
      ((f16x8*)(a.hist + (size_t)l * a.RM * B_ * H_))[o] = z8;
    }
  }
  for (int i = tid; i < B_ * 17; i += NTHR) hlds[i] = 0.f;
  for (int l = 0; l < 4; ++l) {
    const int In = l ? H_ : IN0_;
    const int K = In + H_;
    const int NKB = K / 32;
    const float* Wih = a.Wih[l];
    const float* Whh = a.Whh[l];
    f16* wp = a.wpack + WOFF_[l];
    const int nunits = 3 * H_ * K / 8;
    for (int uu = gtid; uu < nunits; uu += NT) {
      int lane = uu & 63;
      int q = uu >> 6;
      int kb = q % NKB; q /= NKB;
      int gate = q % 3;
      int subb = q / 3;
      int j = subb * 16 + (lane & 15);
      int g = gate * H_ + j;
      int k = kb * 32 + (lane >> 4) * 8;
      const float* src = (k < In) ? (Wih + (size_t)g * In + k)
                                  : (Whh + (size_t)g * H_ + (k - In));
      f16x8 vv;
#pragma unroll
      for (int e = 0; e < 8; ++e) vv[e] = (f16)src[e];
      ((f16x8*)wp)[uu] = vv;
    }
  }

  heavy_barrier(a.bar);   // wbl2+inv once: x16/wpack/state-0 stable, caches clean

  // ================= Phase 1: dataflow-synced recurrence ==================
  const int wg = blockIdx.x;
  const int xslot = wg & 7;
  const int layer = xslot >> 1;
  const int sub = (wg >> 3) * 2 + (xslot & 1);

  if (layer == 0) run_layer<IN0_, false>(a, layer, sub, false, red, hlds, hstage);
  else            run_layer<H_, true>(a, layer, sub, layer == 3, red, hlds, hstage);

  heavy_barrier(a.bar);   // full visibility for h32f before FC

  // ================= Phase 2: final FC (verbatim) ========================
  for (int o = gtid; o < B_ * C_; o += NT) {
    const int b = o / C_;
    const int c = o - b * C_;
    const float* hv = a.h32f + (size_t)b * H_;
    const float* wv = a.fcw + (size_t)c * H_;
    float s = a.fcb[c];
    for (int k = 0; k < H_; k += 4) {
      const float4 h4 = *(const float4*)(hv + k);
      const float4 w4 = *(const float4*)(wv + k);
      s = fmaf(h4.x, w4.x, s);
      s = fmaf(h4.y, w4.y, s);
      s = fmaf(h4.z, w4.z, s);
      s = fmaf(h4.w, w4.w, s);
    }
    a.out[o] = s;
  }
}

extern "C" void kernel_launch(void* const* d_in, const int* in_sizes, int n_in,
                              void* d_out, int out_size, void* d_ws, size_t ws_size,
                              hipStream_t stream) {
  Args a;
  a.x = (const float*)d_in[0];
  for (int l = 0; l < 4; ++l) {
    a.Wih[l] = (const float*)d_in[1 + 4 * l];
    a.Whh[l] = (const float*)d_in[2 + 4 * l];
    a.bih[l] = (const float*)d_in[3 + 4 * l];
    a.bhh[l] = (const float*)d_in[4 + 4 * l];
  }
  a.fcw = (const float*)d_in[17];
  a.fcb = (const float*)d_in[18];
  a.out = (float*)d_out;

  const size_t fixed = 23592960ul * 2        // wpack 45 MiB
                     + 16777216ul * 2        // x16 32 MiB
                     + (size_t)B_ * H_ * 4   // h32f
                     + NWG * 32 * sizeof(int) + 4 * 32 * sizeof(int) + 256;
  const int cand[] = {T_ + 1, 257, 129, 65, 33, 17};
  int RM = 17;
  for (int i = 0; i < 6; ++i) {
    size_t need = fixed + 4ul * cand[i] * B_ * H_ * 2;
    if (need <= ws_size) { RM = cand[i]; break; }
  }
  a.RM = RM;

  char* ws = (char*)d_ws;
  size_t off = 0;
  a.wpack = (f16*)(ws + off); off += 23592960ul * 2;
  a.x16   = (f16*)(ws + off); off += 16777216ul * 2;
  a.hist  = (f16*)(ws + off); off += 4ul * RM * B_ * H_ * 2;
  a.h32f  = (float*)(ws + off); off += (size_t)B_ * H_ * 4;
  a.flags = (int*)(ws + off); off += NWG * 32 * sizeof(int);
  a.clk   = (int*)(ws + off); off += 4 * 32 * sizeof(int);
  a.bar   = (int*)(ws + off); off += 256;

  hipMemsetAsync(a.flags, 0,
                 NWG * 32 * sizeof(int) + 4 * 32 * sizeof(int) + 256, stream);

  void* params[] = { &a };
  hipError_t err = hipLaunchCooperativeKernel((void*)gru_pipeline, dim3(NWG),
                                              dim3(NTHR), params, 0, stream);
  if (err != hipSuccess) {
    gru_pipeline<<<dim3(NWG), dim3(NTHR), 0, stream>>>(a);
  }
}

// Round 19
// 7692.535 us; speedup vs baseline: 1.5296x; 1.0110x over previous
//
#include <hip/hip_runtime.h>

#define B_ 64
#define T_ 512
#define IN0_ 512
#define H_ 1024
#define C_ 1000
#define NWG 256
#define NTHR 512

typedef _Float16 f16;
typedef _Float16 f16x8 __attribute__((ext_vector_type(8)));
typedef _Float16 f16x4 __attribute__((ext_vector_type(4)));
typedef float f32x4 __attribute__((ext_vector_type(4)));

struct Args {
  const float* x;
  const float* Wih[4];
  const float* Whh[4];
  const float* bih[4];
  const float* bhh[4];
  const float* fcw;
  const float* fcb;
  float* out;
  f16* wpack;
  f16* x16;     // [T][B][512] f16
  f16* hist;    // [4][RM][64][1024] f16 — state s (=h(s-1)) in slot s%RM
  float* h32f;  // [64][1024] f32 final hidden of layer 3 (sc1-written)
  int* flags;   // 256 per-WG monotonic step counters, padded 128B apart
  int* clk;     // 4 layer clocks, padded 128B apart
  int* bar;     // [0]=count, [1]=generation (heavy barrier)
  int RM;       // history slots per layer
};

__device__ __forceinline__ float sigmoid_f(float x) {
  return 1.0f / (1.0f + __expf(-x));
}
__device__ __forceinline__ float tanh_f(float x) {
  return 1.0f - 2.0f / (__expf(2.0f * x) + 1.0f);
}

// HEAVY barrier — R1 VERBATIM (HW-verified). Used twice only.
__device__ __forceinline__ void heavy_barrier(int* bar) {
  __threadfence();
  __syncthreads();
  if (threadIdx.x == 0) {
    int* cnt = bar;
    int* gen = bar + 1;
    int g = __hip_atomic_load(gen, __ATOMIC_RELAXED, __HIP_MEMORY_SCOPE_AGENT);
    int v = __hip_atomic_fetch_add(cnt, 1, __ATOMIC_ACQ_REL, __HIP_MEMORY_SCOPE_AGENT);
    if (v == NWG - 1) {
      __hip_atomic_store(cnt, 0, __ATOMIC_RELAXED, __HIP_MEMORY_SCOPE_AGENT);
      __hip_atomic_store(gen, g + 1, __ATOMIC_RELEASE, __HIP_MEMORY_SCOPE_AGENT);
    } else {
      int cur;
      do {
        __builtin_amdgcn_s_sleep(2);
        cur = __hip_atomic_load(gen, __ATOMIC_ACQUIRE, __HIP_MEMORY_SCOPE_AGENT);
      } while (cur == g);
    }
  }
  __syncthreads();
  __threadfence();
}

// sc1 stores (write-through to coherent L3) — R12..R18-verified paths.
__device__ __forceinline__ void astoreu32(unsigned* p, unsigned v) {
  __hip_atomic_store(p, v, __ATOMIC_RELAXED, __HIP_MEMORY_SCOPE_AGENT);
}
union UF32 { float f; unsigned u; };
__device__ __forceinline__ void astore4(float* p, float v) {
  UF32 c; c.f = v;
  __hip_atomic_store((unsigned*)p, c.u, __ATOMIC_RELAXED,
                     __HIP_MEMORY_SCOPE_AGENT);
}
__device__ __forceinline__ int fload(const int* f) {
  return __hip_atomic_load(f, __ATOMIC_RELAXED, __HIP_MEMORY_SCOPE_AGENT);
}
__device__ __forceinline__ void fstore(int* f, int v) {
  __hip_atomic_store(f, v, __ATOMIC_RELAXED, __HIP_MEMORY_SCOPE_AGENT);
}

// Packed-weight layer offsets in f16 elements (R6-verified repack layout).
__constant__ __device__ const size_t WOFF_[4] = {0ul, 4718592ul, 11010048ul, 17301504ul};

// 32 KiB scalar-LDS reduction slot: quantity q (R,Z,NX,NH), slot s in {0,1}.
__device__ __forceinline__ int ridx2(int q, int s, int rb, int i, int lane) {
  return (((q * 2 + s) * 4 + rb) * 4 + i) * 64 + lane;
}

// 8-wave K-slice layer. vs R18: SLICE=NKB/8 (weights 96 VGPR/wave — full
// residency fits allocator's 256 cap), VOLATILE weight gather (cannot be
// rematerialized -> must stay in registers), skip-dead MFMA (pure-x/pure-h
// waves emit 3 MFMAs/kk), 4-phase 2-slot reduction, 8-wave epilogue.
// Waits/flags/drain protocol = R18 verbatim (HSTART generalized).
template <int IN, bool XA>
__device__ void run_layer(const Args& a, int layer, int sub, bool is_last,
                          float* red, float* hlds, f16* hstage) {
  constexpr int NKB = (IN + H_) / 32;   // 48 (layer0) or 64
  constexpr int NXB = IN / 32;          // 16 or 32
  constexpr int SLICE = NKB / 8;        // 6 or 8
  constexpr int HSTART = NXB / SLICE;   // 2 (layer0) or 4

  const int tid = threadIdx.x;
  const int wave = tid >> 6;            // 0..7
  const int lane = tid & 63;
  const int jc = lane & 15;
  const int kg = lane >> 4;
  const int j = sub * 16 + jc;
  const int wbase = wave * SLICE;
  const bool hasX = (wbase < NXB);
  const bool hasH = (wbase + SLICE > NXB);
  const int fid = layer * 64 + sub;
  const int RM = a.RM;

  const float bir = a.bih[layer][j], bhr = a.bhh[layer][j];
  const float biz = a.bih[layer][H_ + j], bhz = a.bhh[layer][H_ + j];
  const float bin_ = a.bih[layer][2 * H_ + j], bhn = a.bhh[layer][2 * H_ + j];

  // ---- VOLATILE weight gather: forced register residency ----
  const volatile f16x8* wpb =
      (const volatile f16x8*)(a.wpack + WOFF_[layer] +
                              (size_t)sub * 3 * NKB * 512) + lane;
  f16x8 wfR[SLICE], wfZ[SLICE], wfN[SLICE];
#pragma unroll
  for (int kk = 0; kk < SLICE; ++kk) {
    wfR[kk] = wpb[(size_t)(0 * NKB + wbase + kk) * 64];
    wfZ[kk] = wpb[(size_t)(1 * NKB + wbase + kk) * 64];
    wfN[kk] = wpb[(size_t)(2 * NKB + wbase + kk) * 64];
  }

  f16* hring = a.hist + (size_t)layer * RM * B_ * H_;
  const f16* xring = XA ? a.hist + (size_t)(layer - 1) * RM * B_ * H_
                        : (const f16*)nullptr;

  for (int t = 0; t < T_; ++t) {
    // ---- per-wave dataflow waits (R18-verified protocol) ----
    if (sub == 0) {
      if (hasH) {
        if (t >= 1) {                    // raw peer flags, lane l <-> peer l
          const int* f = a.flags + (layer * 64 + lane) * 32;
          while (fload(f) < t) __builtin_amdgcn_s_sleep(1);
        }
        if (wave == HSTART && lane == 0)
          fstore(a.clk + layer * 32, t); // publish layer clock
      } else if (XA) {
        if (lane == 0) {
          const int* c = a.clk + (layer - 1) * 32;
          while (fload(c) < t + 1) __builtin_amdgcn_s_sleep(1);
        }
      }
    } else {
      if (hasH) {
        if (t >= 1 && lane == 0) {
          const int* c = a.clk + layer * 32;
          while (fload(c) < t) __builtin_amdgcn_s_sleep(1);
        }
      } else if (XA) {
        if (lane == 0) {
          const int* c = a.clk + (layer - 1) * 32;
          while (fload(c) < t + 1) __builtin_amdgcn_s_sleep(1);
        }
      }
    }
    if (wave == 0 && lane == 1 && layer < 3 && t + 1 >= RM) {
      const int* c = a.clk + (layer + 1) * 32;   // slot-reuse guard
      while (fload(c) < t + 2 - RM) __builtin_amdgcn_s_sleep(1);
    }

    const f16* xbase = XA ? (xring + (size_t)((t + 1) % RM) * B_ * H_)
                          : (a.x16 + (size_t)t * B_ * IN0_);
    const f16* hbase = hring + (size_t)(t % RM) * B_ * H_;
    f16* ho = hring + (size_t)((t + 1) % RM) * B_ * H_;

    f32x4 aR[4], aZ[4], aNX[4], aNH[4];
#pragma unroll
    for (int rb = 0; rb < 4; ++rb) {
      aR[rb] = 0.f; aZ[rb] = 0.f; aNX[rb] = 0.f; aNH[rb] = 0.f;
    }

// ORDINARY cached loads (write-once history — R17-verified).
#define LOADRB(BUF, RB)                                                      \
  do {                                                                       \
    const int arow_ = (RB) * 16 + jc;                                        \
    const f16* xrow_ = xbase + (size_t)arow_ * IN + kg * 8;                  \
    const f16* hrow_ = hbase + (size_t)arow_ * H_ + kg * 8;                  \
    _Pragma("unroll")                                                        \
    for (int kk = 0; kk < SLICE; ++kk) {                                     \
      const int kb_ = wbase + kk;                                            \
      BUF[kk] = (kb_ < NXB) ? *(const f16x8*)(xrow_ + kb_ * 32)              \
                            : *(const f16x8*)(hrow_ + (kb_ - NXB) * 32);     \
    }                                                                        \
  } while (0)

// Skip-dead MFMA: pure-x waves -> R,Z,NX; pure-h -> R,Z,NH; mixed -> selects.
#define MFMARB(BUF, RB)                                                      \
  do {                                                                       \
    if (!hasH) {                                                             \
      _Pragma("unroll")                                                      \
      for (int kk = 0; kk < SLICE; ++kk) {                                   \
        const f16x8 af_ = BUF[kk];                                           \
        aR[RB] = __builtin_amdgcn_mfma_f32_16x16x32_f16(af_, wfR[kk], aR[RB], 0, 0, 0); \
        aZ[RB] = __builtin_amdgcn_mfma_f32_16x16x32_f16(af_, wfZ[kk], aZ[RB], 0, 0, 0); \
        aNX[RB] = __builtin_amdgcn_mfma_f32_16x16x32_f16(af_, wfN[kk], aNX[RB], 0, 0, 0); \
      }                                                                      \
    } else if (!hasX) {                                                      \
      _Pragma("unroll")                                                      \
      for (int kk = 0; kk < SLICE; ++kk) {                                   \
        const f16x8 af_ = BUF[kk];                                           \
        aR[RB] = __builtin_amdgcn_mfma_f32_16x16x32_f16(af_, wfR[kk], aR[RB], 0, 0, 0); \
        aZ[RB] = __builtin_amdgcn_mfma_f32_16x16x32_f16(af_, wfZ[kk], aZ[RB], 0, 0, 0); \
        aNH[RB] = __builtin_amdgcn_mfma_f32_16x16x32_f16(af_, wfN[kk], aNH[RB], 0, 0, 0); \
      }                                                                      \
    } else {                                                                 \
      _Pragma("unroll")                                                      \
      for (int kk = 0; kk < SLICE; ++kk) {                                   \
        const int kb_ = wbase + kk;                                          \
        const bool isx_ = kb_ < NXB;                                         \
        const f16x8 af_ = BUF[kk];                                           \
        aR[RB] = __builtin_amdgcn_mfma_f32_16x16x32_f16(af_, wfR[kk], aR[RB], 0, 0, 0); \
        aZ[RB] = __builtin_amdgcn_mfma_f32_16x16x32_f16(af_, wfZ[kk], aZ[RB], 0, 0, 0); \
        const f16x8 z8_ = {0, 0, 0, 0, 0, 0, 0, 0};                          \
        const f16x8 afx_ = isx_ ? af_ : z8_;                                 \
        const f16x8 afh_ = isx_ ? z8_ : af_;                                 \
        aNX[RB] = __builtin_amdgcn_mfma_f32_16x16x32_f16(afx_, wfN[kk], aNX[RB], 0, 0, 0); \
        aNH[RB] = __builtin_amdgcn_mfma_f32_16x16x32_f16(afh_, wfN[kk], aNH[RB], 0, 0, 0); \
      }                                                                      \
    }                                                                        \
  } while (0)

    {
      f16x8 bufA[SLICE], bufB[SLICE];
      LOADRB(bufA, 0);
      LOADRB(bufB, 1);
      MFMARB(bufA, 0);
      LOADRB(bufA, 2);
      MFMARB(bufB, 1);
      LOADRB(bufB, 3);
      MFMARB(bufA, 2);
      MFMARB(bufB, 3);
    }
#undef LOADRB
#undef MFMARB

    // ---- 4-phase 2-slot scalar-LDS reduction (deterministic) ----
    if (wave < 2) {                      // phase A: waves 0,1 write slot=wave
#pragma unroll
      for (int rb = 0; rb < 4; ++rb)
#pragma unroll
        for (int i = 0; i < 4; ++i) {
          red[ridx2(0, wave, rb, i, lane)] = aR[rb][i];
          red[ridx2(1, wave, rb, i, lane)] = aZ[rb][i];
          red[ridx2(2, wave, rb, i, lane)] = hasX ? aNX[rb][i] : 0.f;
          red[ridx2(3, wave, rb, i, lane)] = hasH ? aNH[rb][i] : 0.f;
        }
    }
    __syncthreads();
    if (wave == 2 || wave == 3) {        // phase B: add slot=wave-2
      const int s = wave - 2;
#pragma unroll
      for (int rb = 0; rb < 4; ++rb)
#pragma unroll
        for (int i = 0; i < 4; ++i) {
          red[ridx2(0, s, rb, i, lane)] += aR[rb][i];
          red[ridx2(1, s, rb, i, lane)] += aZ[rb][i];
          if (hasX) red[ridx2(2, s, rb, i, lane)] += aNX[rb][i];
          if (hasH) red[ridx2(3, s, rb, i, lane)] += aNH[rb][i];
        }
    }
    __syncthreads();
    if (wave == 4 || wave == 5) {        // phase C: add slot=wave-4
      const int s = wave - 4;
#pragma unroll
      for (int rb = 0; rb < 4; ++rb)
#pragma unroll
        for (int i = 0; i < 4; ++i) {
          red[ridx2(0, s, rb, i, lane)] += aR[rb][i];
          red[ridx2(1, s, rb, i, lane)] += aZ[rb][i];
          if (hasX) red[ridx2(2, s, rb, i, lane)] += aNX[rb][i];
          if (hasH) red[ridx2(3, s, rb, i, lane)] += aNH[rb][i];
        }
    }
    __syncthreads();
    if (wave == 6 || wave == 7) {        // phase D: add slot=wave-6
      const int s = wave - 6;
#pragma unroll
      for (int rb = 0; rb < 4; ++rb)
#pragma unroll
        for (int i = 0; i < 4; ++i) {
          red[ridx2(0, s, rb, i, lane)] += aR[rb][i];
          red[ridx2(1, s, rb, i, lane)] += aZ[rb][i];
          if (hasX) red[ridx2(2, s, rb, i, lane)] += aNX[rb][i];
          if (hasH) red[ridx2(3, s, rb, i, lane)] += aNH[rb][i];
        }
    }
    __syncthreads();

    // ---- 8-wave epilogue: wave -> (rb = wave>>1, i-half = (wave&1)*2) ----
    {
      const int rb = wave >> 1;
      const int ib = (wave & 1) * 2;
#pragma unroll
      for (int ii = 0; ii < 2; ++ii) {
        const int i = ib + ii;
        const int b = rb * 16 + kg * 4 + i;
        const float R  = red[ridx2(0, 0, rb, i, lane)] + red[ridx2(0, 1, rb, i, lane)];
        const float Z  = red[ridx2(1, 0, rb, i, lane)] + red[ridx2(1, 1, rb, i, lane)];
        const float NX = red[ridx2(2, 0, rb, i, lane)] + red[ridx2(2, 1, rb, i, lane)];
        const float NH = red[ridx2(3, 0, rb, i, lane)] + red[ridx2(3, 1, rb, i, lane)];
        const float r = sigmoid_f(R + bir + bhr);
        const float zz = sigmoid_f(Z + biz + bhz);
        const float nn = tanh_f(NX + bin_ + r * (NH + bhn));
        const float hp = hlds[b * 17 + jc];
        const float hnew = (1.0f - zz) * nn + zz * hp;
        hlds[b * 17 + jc] = hnew;
        hstage[b * 20 + jc] = (f16)hnew;
        if (is_last && t == T_ - 1) astore4(&a.h32f[(size_t)b * H_ + j], hnew);
      }
    }
    __syncthreads();
    // ---- coalesced h write: 512 threads x aligned 4B sc1 stores ----
    {
      const int b = tid >> 3;            // 0..63
      const int c = tid & 7;             // 0..7 (4B chunk of 16 f16)
      const unsigned v = *(const unsigned*)&hstage[b * 20 + c * 2];
      astoreu32((unsigned*)&ho[(size_t)b * H_ + sub * 16 + c * 2], v);
    }

    // ---- signal: drain sc1 data to L3, then publish flag (R12 protocol) ----
    asm volatile("s_waitcnt vmcnt(0) lgkmcnt(0)" ::: "memory");
    __syncthreads();
    if (tid == 0) fstore(a.flags + fid * 32, t + 1);
  }

  // final clock publish (consumers' last x-wait needs clk >= T_)
  if (sub == 0 && layer < 3 && wave == 0) {
    const int* f = a.flags + (layer * 64 + lane) * 32;
    while (fload(f) < T_) __builtin_amdgcn_s_sleep(1);
    if (lane == 0) fstore(a.clk + layer * 32, T_);
  }
}

__global__ void __launch_bounds__(NTHR) gru_pipeline(Args a) {
  __shared__ float red[4 * 2 * 4 * 4 * 64];   // 32 KiB scalar f32
  __shared__ float hlds[B_ * 17];             // 4.25 KiB h-master
  __shared__ f16 hstage[B_ * 20];             // 2.5 KiB h' staging

  const int tid = threadIdx.x;
  const int gtid = blockIdx.x * NTHR + tid;
  const int NT = NWG * NTHR;

  // ================= Phase 0: prologue (R6..R18 verbatim) =================
  {
    const int nf4 = B_ * T_ * IN0_ / 4;
    for (int i = gtid; i < nf4; i += NT) {
      int k4 = i & 127;
      int q = i >> 7;
      int b = q & 63;
      int t = q >> 6;
      const float4 v = *(const float4*)(a.x + ((size_t)b * T_ + t) * IN0_ + k4 * 4);
      f16x4 o;
      o[0] = (f16)v.x; o[1] = (f16)v.y; o[2] = (f16)v.z; o[3] = (f16)v.w;
      *(f16x4*)(a.x16 + (size_t)i * 4) = o;
    }
  }
  // zero ONLY state-0 slots (h(-1)=0) of each layer's history.
  {
    f16x8 z8 = {0, 0, 0, 0, 0, 0, 0, 0};
    for (int i = gtid; i < 4 * B_ * H_ / 8; i += NT) {
      int l = i / (B_ * H_ / 8);
      int o = i - l * (B_ * H_ / 8);
      ((f16x8*)(a.hist + (size_t)l * a.RM * B_ * H_))[o] = z8;
    }
  }
  for (int i = tid; i < B_ * 17; i += NTHR) hlds[i] = 0.f;
  for (int l = 0; l < 4; ++l) {
    const int In = l ? H_ : IN0_;
    const int K = In + H_;
    const int NKB = K / 32;
    const float* Wih = a.Wih[l];
    const float* Whh = a.Whh[l];
    f16* wp = a.wpack + WOFF_[l];
    const int nunits = 3 * H_ * K / 8;
    for (int uu = gtid; uu < nunits; uu += NT) {
      int lane = uu & 63;
      int q = uu >> 6;
      int kb = q % NKB; q /= NKB;
      int gate = q % 3;
      int subb = q / 3;
      int j = subb * 16 + (lane & 15);
      int g = gate * H_ + j;
      int k = kb * 32 + (lane >> 4) * 8;
      const float* src = (k < In) ? (Wih + (size_t)g * In + k)
                                  : (Whh + (size_t)g * H_ + (k - In));
      f16x8 vv;
#pragma unroll
      for (int e = 0; e < 8; ++e) vv[e] = (f16)src[e];
      ((f16x8*)wp)[uu] = vv;
    }
  }

  heavy_barrier(a.bar);   // wbl2+inv once: x16/wpack/state-0 stable

  // ================= Phase 1: dataflow-synced recurrence ==================
  const int wg = blockIdx.x;
  const int xslot = wg & 7;
  const int layer = xslot >> 1;
  const int sub = (wg >> 3) * 2 + (xslot & 1);

  if (layer == 0) run_layer<IN0_, false>(a, layer, sub, false, red, hlds, hstage);
  else            run_layer<H_, true>(a, layer, sub, layer == 3, red, hlds, hstage);

  heavy_barrier(a.bar);   // full visibility for h32f before FC

  // ================= Phase 2: final FC (verbatim) ========================
  for (int o = gtid; o < B_ * C_; o += NT) {
    const int b = o / C_;
    const int c = o - b * C_;
    const float* hv = a.h32f + (size_t)b * H_;
    const float* wv = a.fcw + (size_t)c * H_;
    float s = a.fcb[c];
    for (int k = 0; k < H_; k += 4) {
      const float4 h4 = *(const float4*)(hv + k);
      const float4 w4 = *(const float4*)(wv + k);
      s = fmaf(h4.x, w4.x, s);
      s = fmaf(h4.y, w4.y, s);
      s = fmaf(h4.z, w4.z, s);
      s = fmaf(h4.w, w4.w, s);
    }
    a.out[o] = s;
  }
}

extern "C" void kernel_launch(void* const* d_in, const int* in_sizes, int n_in,
                              void* d_out, int out_size, void* d_ws, size_t ws_size,
                              hipStream_t stream) {
  Args a;
  a.x = (const float*)d_in[0];
  for (int l = 0; l < 4; ++l) {
    a.Wih[l] = (const float*)d_in[1 + 4 * l];
    a.Whh[l] = (const float*)d_in[2 + 4 * l];
    a.bih[l] = (const float*)d_in[3 + 4 * l];
    a.bhh[l] = (const float*)d_in[4 + 4 * l];
  }
  a.fcw = (const float*)d_in[17];
  a.fcb = (const float*)d_in[18];
  a.out = (float*)d_out;

  const size_t fixed = 23592960ul * 2        // wpack 45 MiB
                     + 16777216ul * 2        // x16 32 MiB
                     + (size_t)B_ * H_ * 4   // h32f
                     + NWG * 32 * sizeof(int) + 4 * 32 * sizeof(int) + 256;
  const int cand[] = {T_ + 1, 257, 129, 65, 33, 17};
  int RM = 17;
  for (int i = 0; i < 6; ++i) {
    size_t need = fixed + 4ul * cand[i] * B_ * H_ * 2;
    if (need <= ws_size) { RM = cand[i]; break; }
  }
  a.RM = RM;

  char* ws = (char*)d_ws;
  size_t off = 0;
  a.wpack = (f16*)(ws + off); off += 23592960ul * 2;
  a.x16   = (f16*)(ws + off); off += 16777216ul * 2;
  a.hist  = (f16*)(ws + off); off += 4ul * RM * B_ * H_ * 2;
  a.h32f  = (float*)(ws + off); off += (size_t)B_ * H_ * 4;
  a.flags = (int*)(ws + off); off += NWG * 32 * sizeof(int);
  a.clk   = (int*)(ws + off); off += 4 * 32 * sizeof(int);
  a.bar   = (int*)(ws + off); off += 256;

  hipMemsetAsync(a.flags, 0,
                 NWG * 32 * sizeof(int) + 4 * 32 * sizeof(int) + 256, stream);

  void* params[] = { &a };
  hipError_t err = hipLaunchCooperativeKernel((void*)gru_pipeline, dim3(NWG),
                                              dim3(NTHR), params, 0, stream);
  if (err != hipSuccess) {
    gru_pipeline<<<dim3(NWG), dim3(NTHR), 0, stream>>>(a);
  }
}

// Round 20
// 7680.878 us; speedup vs baseline: 1.5320x; 1.0015x over previous
//
#include <hip/hip_runtime.h>

#define B_ 64
#define T_ 512
#define IN0_ 512
#define H_ 1024
#define C_ 1000
#define NWG 256
#define NTHR 512

typedef _Float16 f16;
typedef _Float16 f16x8 __attribute__((ext_vector_type(8)));
typedef _Float16 f16x4 __attribute__((ext_vector_type(4)));
typedef float f32x4 __attribute__((ext_vector_type(4)));

struct Args {
  const float* x;
  const float* Wih[4];
  const float* Whh[4];
  const float* bih[4];
  const float* bhh[4];
  const float* fcw;
  const float* fcb;
  float* out;
  f16* wpack;
  f16* x16;     // [T][B][512] f16
  f16* hist;    // [4][RM][64][1024] f16 — state s (=h(s-1)) in slot s%RM
  float* h32f;  // [64][1024] f32 final hidden of layer 3 (sc1-written)
  int* flags;   // 256 per-WG monotonic step counters, padded 128B apart
  int* clk;     // 4 layer clocks, padded 128B apart
  int* bar;     // [0]=count, [1]=generation (heavy barrier)
  int RM;       // history slots per layer
};

__device__ __forceinline__ float sigmoid_f(float x) {
  return 1.0f / (1.0f + __expf(-x));
}
__device__ __forceinline__ float tanh_f(float x) {
  return 1.0f - 2.0f / (__expf(2.0f * x) + 1.0f);
}

// HEAVY barrier — R1 VERBATIM (HW-verified). Used twice only.
__device__ __forceinline__ void heavy_barrier(int* bar) {
  __threadfence();
  __syncthreads();
  if (threadIdx.x == 0) {
    int* cnt = bar;
    int* gen = bar + 1;
    int g = __hip_atomic_load(gen, __ATOMIC_RELAXED, __HIP_MEMORY_SCOPE_AGENT);
    int v = __hip_atomic_fetch_add(cnt, 1, __ATOMIC_ACQ_REL, __HIP_MEMORY_SCOPE_AGENT);
    if (v == NWG - 1) {
      __hip_atomic_store(cnt, 0, __ATOMIC_RELAXED, __HIP_MEMORY_SCOPE_AGENT);
      __hip_atomic_store(gen, g + 1, __ATOMIC_RELEASE, __HIP_MEMORY_SCOPE_AGENT);
    } else {
      int cur;
      do {
        __builtin_amdgcn_s_sleep(2);
        cur = __hip_atomic_load(gen, __ATOMIC_ACQUIRE, __HIP_MEMORY_SCOPE_AGENT);
      } while (cur == g);
    }
  }
  __syncthreads();
  __threadfence();
}

// sc1 stores (write-through to coherent L3) — R12..R19-verified paths.
__device__ __forceinline__ void astoreu32(unsigned* p, unsigned v) {
  __hip_atomic_store(p, v, __ATOMIC_RELAXED, __HIP_MEMORY_SCOPE_AGENT);
}
union UF32 { float f; unsigned u; };
__device__ __forceinline__ void astore4(float* p, float v) {
  UF32 c; c.f = v;
  __hip_atomic_store((unsigned*)p, c.u, __ATOMIC_RELAXED,
                     __HIP_MEMORY_SCOPE_AGENT);
}
__device__ __forceinline__ int fload(const int* f) {
  return __hip_atomic_load(f, __ATOMIC_RELAXED, __HIP_MEMORY_SCOPE_AGENT);
}
__device__ __forceinline__ void fstore(int* f, int v) {
  __hip_atomic_store(f, v, __ATOMIC_RELAXED, __HIP_MEMORY_SCOPE_AGENT);
}

// Packed-weight layer offsets in f16 elements (R6-verified repack layout).
__constant__ __device__ const size_t WOFF_[4] = {0ul, 4718592ul, 11010048ul, 17301504ul};

// 32 KiB scalar-LDS reduction slot: quantity q (R,Z,NX,NH), slot s in {0,1}.
__device__ __forceinline__ int ridx2(int q, int s, int rb, int i, int lane) {
  return (((q * 2 + s) * 4 + rb) * 4 + i) * 64 + lane;
}

// R19-VERIFIED 8-wave K-slice layer. ONLY change: the kernel is now declared
// __launch_bounds__(512, 2) — 2 waves/SIMD => 256-VGPR cap — so the VOLATILE
// weight arrays (96 VGPR) + acc (64) + bufs (64) actually FIT and the
// allocator keeps weights register-resident instead of spilling/streaming.
template <int IN, bool XA>
__device__ void run_layer(const Args& a, int layer, int sub, bool is_last,
                          float* red, float* hlds, f16* hstage) {
  constexpr int NKB = (IN + H_) / 32;   // 48 (layer0) or 64
  constexpr int NXB = IN / 32;          // 16 or 32
  constexpr int SLICE = NKB / 8;        // 6 or 8
  constexpr int HSTART = NXB / SLICE;   // 2 (layer0) or 4

  const int tid = threadIdx.x;
  const int wave = tid >> 6;            // 0..7
  const int lane = tid & 63;
  const int jc = lane & 15;
  const int kg = lane >> 4;
  const int j = sub * 16 + jc;
  const int wbase = wave * SLICE;
  const bool hasX = (wbase < NXB);
  const bool hasH = (wbase + SLICE > NXB);
  const int fid = layer * 64 + sub;
  const int RM = a.RM;

  const float bir = a.bih[layer][j], bhr = a.bhh[layer][j];
  const float biz = a.bih[layer][H_ + j], bhz = a.bhh[layer][H_ + j];
  const float bin_ = a.bih[layer][2 * H_ + j], bhn = a.bhh[layer][2 * H_ + j];

  // ---- VOLATILE weight gather: forced register residency ----
  const volatile f16x8* wpb =
      (const volatile f16x8*)(a.wpack + WOFF_[layer] +
                              (size_t)sub * 3 * NKB * 512) + lane;
  f16x8 wfR[SLICE], wfZ[SLICE], wfN[SLICE];
#pragma unroll
  for (int kk = 0; kk < SLICE; ++kk) {
    wfR[kk] = wpb[(size_t)(0 * NKB + wbase + kk) * 64];
    wfZ[kk] = wpb[(size_t)(1 * NKB + wbase + kk) * 64];
    wfN[kk] = wpb[(size_t)(2 * NKB + wbase + kk) * 64];
  }

  f16* hring = a.hist + (size_t)layer * RM * B_ * H_;
  const f16* xring = XA ? a.hist + (size_t)(layer - 1) * RM * B_ * H_
                        : (const f16*)nullptr;

  for (int t = 0; t < T_; ++t) {
    // ---- per-wave dataflow waits (R18/R19-verified protocol) ----
    if (sub == 0) {
      if (hasH) {
        if (t >= 1) {                    // raw peer flags, lane l <-> peer l
          const int* f = a.flags + (layer * 64 + lane) * 32;
          while (fload(f) < t) __builtin_amdgcn_s_sleep(1);
        }
        if (wave == HSTART && lane == 0)
          fstore(a.clk + layer * 32, t); // publish layer clock
      } else if (XA) {
        if (lane == 0) {
          const int* c = a.clk + (layer - 1) * 32;
          while (fload(c) < t + 1) __builtin_amdgcn_s_sleep(1);
        }
      }
    } else {
      if (hasH) {
        if (t >= 1 && lane == 0) {
          const int* c = a.clk + layer * 32;
          while (fload(c) < t) __builtin_amdgcn_s_sleep(1);
        }
      } else if (XA) {
        if (lane == 0) {
          const int* c = a.clk + (layer - 1) * 32;
          while (fload(c) < t + 1) __builtin_amdgcn_s_sleep(1);
        }
      }
    }
    if (wave == 0 && lane == 1 && layer < 3 && t + 1 >= RM) {
      const int* c = a.clk + (layer + 1) * 32;   // slot-reuse guard
      while (fload(c) < t + 2 - RM) __builtin_amdgcn_s_sleep(1);
    }

    const f16* xbase = XA ? (xring + (size_t)((t + 1) % RM) * B_ * H_)
                          : (a.x16 + (size_t)t * B_ * IN0_);
    const f16* hbase = hring + (size_t)(t % RM) * B_ * H_;
    f16* ho = hring + (size_t)((t + 1) % RM) * B_ * H_;

    f32x4 aR[4], aZ[4], aNX[4], aNH[4];
#pragma unroll
    for (int rb = 0; rb < 4; ++rb) {
      aR[rb] = 0.f; aZ[rb] = 0.f; aNX[rb] = 0.f; aNH[rb] = 0.f;
    }

// ORDINARY cached loads (write-once history — R17-verified).
#define LOADRB(BUF, RB)                                                      \
  do {                                                                       \
    const int arow_ = (RB) * 16 + jc;                                        \
    const f16* xrow_ = xbase + (size_t)arow_ * IN + kg * 8;                  \
    const f16* hrow_ = hbase + (size_t)arow_ * H_ + kg * 8;                  \
    _Pragma("unroll")                                                        \
    for (int kk = 0; kk < SLICE; ++kk) {                                     \
      const int kb_ = wbase + kk;                                            \
      BUF[kk] = (kb_ < NXB) ? *(const f16x8*)(xrow_ + kb_ * 32)              \
                            : *(const f16x8*)(hrow_ + (kb_ - NXB) * 32);     \
    }                                                                        \
  } while (0)

// Skip-dead MFMA: pure-x waves -> R,Z,NX; pure-h -> R,Z,NH; mixed -> selects.
#define MFMARB(BUF, RB)                                                      \
  do {                                                                       \
    if (!hasH) {                                                             \
      _Pragma("unroll")                                                      \
      for (int kk = 0; kk < SLICE; ++kk) {                                   \
        const f16x8 af_ = BUF[kk];                                           \
        aR[RB] = __builtin_amdgcn_mfma_f32_16x16x32_f16(af_, wfR[kk], aR[RB], 0, 0, 0); \
        aZ[RB] = __builtin_amdgcn_mfma_f32_16x16x32_f16(af_, wfZ[kk], aZ[RB], 0, 0, 0); \
        aNX[RB] = __builtin_amdgcn_mfma_f32_16x16x32_f16(af_, wfN[kk], aNX[RB], 0, 0, 0); \
      }                                                                      \
    } else if (!hasX) {                                                      \
      _Pragma("unroll")                                                      \
      for (int kk = 0; kk < SLICE; ++kk) {                                   \
        const f16x8 af_ = BUF[kk];                                           \
        aR[RB] = __builtin_amdgcn_mfma_f32_16x16x32_f16(af_, wfR[kk], aR[RB], 0, 0, 0); \
        aZ[RB] = __builtin_amdgcn_mfma_f32_16x16x32_f16(af_, wfZ[kk], aZ[RB], 0, 0, 0); \
        aNH[RB] = __builtin_amdgcn_mfma_f32_16x16x32_f16(af_, wfN[kk], aNH[RB], 0, 0, 0); \
      }                                                                      \
    } else {                                                                 \
      _Pragma("unroll")                                                      \
      for (int kk = 0; kk < SLICE; ++kk) {                                   \
        const int kb_ = wbase + kk;                                          \
        const bool isx_ = kb_ < NXB;                                         \
        const f16x8 af_ = BUF[kk];                                           \
        aR[RB] = __builtin_amdgcn_mfma_f32_16x16x32_f16(af_, wfR[kk], aR[RB], 0, 0, 0); \
        aZ[RB] = __builtin_amdgcn_mfma_f32_16x16x32_f16(af_, wfZ[kk], aZ[RB], 0, 0, 0); \
        const f16x8 z8_ = {0, 0, 0, 0, 0, 0, 0, 0};                          \
        const f16x8 afx_ = isx_ ? af_ : z8_;                                 \
        const f16x8 afh_ = isx_ ? z8_ : af_;                                 \
        aNX[RB] = __builtin_amdgcn_mfma_f32_16x16x32_f16(afx_, wfN[kk], aNX[RB], 0, 0, 0); \
        aNH[RB] = __builtin_amdgcn_mfma_f32_16x16x32_f16(afh_, wfN[kk], aNH[RB], 0, 0, 0); \
      }                                                                      \
    }                                                                        \
  } while (0)

    {
      f16x8 bufA[SLICE], bufB[SLICE];
      LOADRB(bufA, 0);
      LOADRB(bufB, 1);
      MFMARB(bufA, 0);
      LOADRB(bufA, 2);
      MFMARB(bufB, 1);
      LOADRB(bufB, 3);
      MFMARB(bufA, 2);
      MFMARB(bufB, 3);
    }
#undef LOADRB
#undef MFMARB

    // ---- 4-phase 2-slot scalar-LDS reduction (R19-verified) ----
    if (wave < 2) {                      // phase A: waves 0,1 write slot=wave
#pragma unroll
      for (int rb = 0; rb < 4; ++rb)
#pragma unroll
        for (int i = 0; i < 4; ++i) {
          red[ridx2(0, wave, rb, i, lane)] = aR[rb][i];
          red[ridx2(1, wave, rb, i, lane)] = aZ[rb][i];
          red[ridx2(2, wave, rb, i, lane)] = hasX ? aNX[rb][i] : 0.f;
          red[ridx2(3, wave, rb, i, lane)] = hasH ? aNH[rb][i] : 0.f;
        }
    }
    __syncthreads();
    if (wave == 2 || wave == 3) {        // phase B: add slot=wave-2
      const int s = wave - 2;
#pragma unroll
      for (int rb = 0; rb < 4; ++rb)
#pragma unroll
        for (int i = 0; i < 4; ++i) {
          red[ridx2(0, s, rb, i, lane)] += aR[rb][i];
          red[ridx2(1, s, rb, i, lane)] += aZ[rb][i];
          if (hasX) red[ridx2(2, s, rb, i, lane)] += aNX[rb][i];
          if (hasH) red[ridx2(3, s, rb, i, lane)] += aNH[rb][i];
        }
    }
    __syncthreads();
    if (wave == 4 || wave == 5) {        // phase C: add slot=wave-4
      const int s = wave - 4;
#pragma unroll
      for (int rb = 0; rb < 4; ++rb)
#pragma unroll
        for (int i = 0; i < 4; ++i) {
          red[ridx2(0, s, rb, i, lane)] += aR[rb][i];
          red[ridx2(1, s, rb, i, lane)] += aZ[rb][i];
          if (hasX) red[ridx2(2, s, rb, i, lane)] += aNX[rb][i];
          if (hasH) red[ridx2(3, s, rb, i, lane)] += aNH[rb][i];
        }
    }
    __syncthreads();
    if (wave == 6 || wave == 7) {        // phase D: add slot=wave-6
      const int s = wave - 6;
#pragma unroll
      for (int rb = 0; rb < 4; ++rb)
#pragma unroll
        for (int i = 0; i < 4; ++i) {
          red[ridx2(0, s, rb, i, lane)] += aR[rb][i];
          red[ridx2(1, s, rb, i, lane)] += aZ[rb][i];
          if (hasX) red[ridx2(2, s, rb, i, lane)] += aNX[rb][i];
          if (hasH) red[ridx2(3, s, rb, i, lane)] += aNH[rb][i];
        }
    }
    __syncthreads();

    // ---- 8-wave epilogue (R19-verified): rb = wave>>1, i-half = (wave&1)*2
    {
      const int rb = wave >> 1;
      const int ib = (wave & 1) * 2;
#pragma unroll
      for (int ii = 0; ii < 2; ++ii) {
        const int i = ib + ii;
        const int b = rb * 16 + kg * 4 + i;
        const float R  = red[ridx2(0, 0, rb, i, lane)] + red[ridx2(0, 1, rb, i, lane)];
        const float Z  = red[ridx2(1, 0, rb, i, lane)] + red[ridx2(1, 1, rb, i, lane)];
        const float NX = red[ridx2(2, 0, rb, i, lane)] + red[ridx2(2, 1, rb, i, lane)];
        const float NH = red[ridx2(3, 0, rb, i, lane)] + red[ridx2(3, 1, rb, i, lane)];
        const float r = sigmoid_f(R + bir + bhr);
        const float zz = sigmoid_f(Z + biz + bhz);
        const float nn = tanh_f(NX + bin_ + r * (NH + bhn));
        const float hp = hlds[b * 17 + jc];
        const float hnew = (1.0f - zz) * nn + zz * hp;
        hlds[b * 17 + jc] = hnew;
        hstage[b * 20 + jc] = (f16)hnew;
        if (is_last && t == T_ - 1) astore4(&a.h32f[(size_t)b * H_ + j], hnew);
      }
    }
    __syncthreads();
    // ---- coalesced h write: 512 threads x aligned 4B sc1 stores ----
    {
      const int b = tid >> 3;            // 0..63
      const int c = tid & 7;             // 0..7 (4B chunk of 16 f16)
      const unsigned v = *(const unsigned*)&hstage[b * 20 + c * 2];
      astoreu32((unsigned*)&ho[(size_t)b * H_ + sub * 16 + c * 2], v);
    }

    // ---- signal: drain sc1 data to L3, then publish flag (R12 protocol) ----
    asm volatile("s_waitcnt vmcnt(0) lgkmcnt(0)" ::: "memory");
    __syncthreads();
    if (tid == 0) fstore(a.flags + fid * 32, t + 1);
  }

  // final clock publish (consumers' last x-wait needs clk >= T_)
  if (sub == 0 && layer < 3 && wave == 0) {
    const int* f = a.flags + (layer * 64 + lane) * 32;
    while (fload(f) < T_) __builtin_amdgcn_s_sleep(1);
    if (lane == 0) fstore(a.clk + layer * 32, T_);
  }
}

__global__ void __launch_bounds__(NTHR, 2) gru_pipeline(Args a) {
  __shared__ float red[4 * 2 * 4 * 4 * 64];   // 32 KiB scalar f32
  __shared__ float hlds[B_ * 17];             // 4.25 KiB h-master
  __shared__ f16 hstage[B_ * 20];             // 2.5 KiB h' staging

  const int tid = threadIdx.x;
  const int gtid = blockIdx.x * NTHR + tid;
  const int NT = NWG * NTHR;

  // ================= Phase 0: prologue (R6..R19 verbatim) =================
  {
    const int nf4 = B_ * T_ * IN0_ / 4;
    for (int i = gtid; i < nf4; i += NT) {
      int k4 = i & 127;
      int q = i >> 7;
      int b = q & 63;
      int t = q >> 6;
      const float4 v = *(const float4*)(a.x + ((size_t)b * T_ + t) * IN0_ + k4 * 4);
      f16x4 o;
      o[0] = (f16)v.x; o[1] = (f16)v.y; o[2] = (f16)v.z; o[3] = (f16)v.w;
      *(f16x4*)(a.x16 + (size_t)i * 4) = o;
    }
  }
  // zero ONLY state-0 slots (h(-1)=0) of each layer's history.
  {
    f16x8 z8 = {0, 0, 0, 0, 0, 0, 0, 0};
    for (int i = gtid; i < 4 * B_ * H_ / 8; i += NT) {
      int l = i / (B_ * H_ / 8);
      int o = i - l * (B_ * H_ / 8);
      ((f16x8*)(a.hist + (size_t)l * a.RM * B_ * H_))[o] = z8;
    }
  }
  for (int i = tid; i < B_ * 17; i += NTHR) hlds[i] = 0.f;
  for (int l = 0; l < 4; ++l) {
    const int In = l ? H_ : IN0_;
    const int K = In + H_;
    const int NKB = K / 32;
    const float* Wih = a.Wih[l];
    const float* Whh = a.Whh[l];
    f16* wp = a.wpack + WOFF_[l];
    const int nunits = 3 * H_ * K / 8;
    for (int uu = gtid; uu < nunits; uu += NT) {
      int lane = uu & 63;
      int q = uu >> 6;
      int kb = q % NKB; q /= NKB;
      int gate = q % 3;
      int subb = q / 3;
      int j = subb * 16 + (lane & 15);
      int g = gate * H_ + j;
      int k = kb * 32 + (lane >> 4) * 8;
      const float* src = (k < In) ? (Wih + (size_t)g * In + k)
                                  : (Whh + (size_t)g * H_ + (k - In));
      f16x8 vv;
#pragma unroll
      for (int e = 0; e < 8; ++e) vv[e] = (f16)src[e];
      ((f16x8*)wp)[uu] = vv;
    }
  }

  heavy_barrier(a.bar);   // wbl2+inv once: x16/wpack/state-0 stable

  // ================= Phase 1: dataflow-synced recurrence ==================
  const int wg = blockIdx.x;
  const int xslot = wg & 7;
  const int layer = xslot >> 1;
  const int sub = (wg >> 3) * 2 + (xslot & 1);

  if (layer == 0) run_layer<IN0_, false>(a, layer, sub, false, red, hlds, hstage);
  else            run_layer<H_, true>(a, layer, sub, layer == 3, red, hlds, hstage);

  heavy_barrier(a.bar);   // full visibility for h32f before FC

  // ================= Phase 2: final FC (verbatim) ========================
  for (int o = gtid; o < B_ * C_; o += NT) {
    const int b = o / C_;
    const int c = o - b * C_;
    const float* hv = a.h32f + (size_t)b * H_;
    const float* wv = a.fcw + (size_t)c * H_;
    float s = a.fcb[c];
    for (int k = 0; k < H_; k += 4) {
      const float4 h4 = *(const float4*)(hv + k);
      const float4 w4 = *(const float4*)(wv + k);
      s = fmaf(h4.x, w4.x, s);
      s = fmaf(h4.y, w4.y, s);
      s = fmaf(h4.z, w4.z, s);
      s = fmaf(h4.w, w4.w, s);
    }
    a.out[o] = s;
  }
}

extern "C" void kernel_launch(void* const* d_in, const int* in_sizes, int n_in,
                              void* d_out, int out_size, void* d_ws, size_t ws_size,
                              hipStream_t stream) {
  Args a;
  a.x = (const float*)d_in[0];
  for (int l = 0; l < 4; ++l) {
    a.Wih[l] = (const float*)d_in[1 + 4 * l];
    a.Whh[l] = (const float*)d_in[2 + 4 * l];
    a.bih[l] = (const float*)d_in[3 + 4 * l];
    a.bhh[l] = (const float*)d_in[4 + 4 * l];
  }
  a.fcw = (const float*)d_in[17];
  a.fcb = (const float*)d_in[18];
  a.out = (float*)d_out;

  const size_t fixed = 23592960ul * 2        // wpack 45 MiB
                     + 16777216ul * 2        // x16 32 MiB
                     + (size_t)B_ * H_ * 4   // h32f
                     + NWG * 32 * sizeof(int) + 4 * 32 * sizeof(int) + 256;
  const int cand[] = {T_ + 1, 257, 129, 65, 33, 17};
  int RM = 17;
  for (int i = 0; i < 6; ++i) {
    size_t need = fixed + 4ul * cand[i] * B_ * H_ * 2;
    if (need <= ws_size) { RM = cand[i]; break; }
  }
  a.RM = RM;

  char* ws = (char*)d_ws;
  size_t off = 0;
  a.wpack = (f16*)(ws + off); off += 23592960ul * 2;
  a.x16   = (f16*)(ws + off); off += 16777216ul * 2;
  a.hist  = (f16*)(ws + off); off += 4ul * RM * B_ * H_ * 2;
  a.h32f  = (float*)(ws + off); off += (size_t)B_ * H_ * 4;
  a.flags = (int*)(ws + off); off += NWG * 32 * sizeof(int);
  a.clk   = (int*)(ws + off); off += 4 * 32 * sizeof(int);
  a.bar   = (int*)(ws + off); off += 256;

  hipMemsetAsync(a.flags, 0,
                 NWG * 32 * sizeof(int) + 4 * 32 * sizeof(int) + 256, stream);

  void* params[] = { &a };
  hipError_t err = hipLaunchCooperativeKernel((void*)gru_pipeline, dim3(NWG),
                                              dim3(NTHR), params, 0, stream);
  if (err != hipSuccess) {
    gru_pipeline<<<dim3(NWG), dim3(NTHR), 0, stream>>>(a);
  }
}